// Round 15
// baseline (519.104 us; speedup 1.0000x reference)
//
#include <hip/hip_runtime.h>
#include <hip/hip_bf16.h>
#include <cstdint>
#include <cstddef>

#define NB      128
#define RR      300
#define EMB     32

typedef __bf16 bf16x8 __attribute__((ext_vector_type(8)));
typedef float  f32x4  __attribute__((ext_vector_type(4)));
typedef unsigned short ushort8 __attribute__((ext_vector_type(8)));

__device__ __forceinline__ unsigned short f2bf(float f) {
    union { __hip_bfloat16 h; unsigned short u; } c;
    c.h = __float2bfloat16(f);
    return c.u;
}
__device__ __forceinline__ float bf2f(unsigned short u) {
    union { __hip_bfloat16 h; unsigned short u; } c;
    c.u = u;
    return __bfloat162float(c.h);
}

// ---------------------------------------------------------------------------
// helpers for the consolidated prep kernel
// ---------------------------------------------------------------------------
__device__ __forceinline__ void wpack_body(
    const float* __restrict__ w, unsigned short* __restrict__ wPT,
    int COUT, int CIN, int KK, int gpc, int idx, int total)
{
    if (idx >= total) return;
    int kk = idx & 31;
    int t  = idx >> 5;
    int oc = t % COUT;
    int kb = t / COUT;
    int g  = kb * 4 + (kk >> 3);
    int j  = kk & 7;
    int shift = g / gpc;
    int ci    = (g % gpc) * 8 + j;
    float v = (shift < KK && ci < CIN)
        ? w[(size_t)oc * CIN * KK + (size_t)ci * KK + shift] : 0.0f;
    wPT[idx] = f2bf(v);
}

__device__ __forceinline__ void fcT_body(
    const float* __restrict__ w, float* __restrict__ wT, int O, int I, int idx)
{
    if (idx >= O * I) return;
    int i = idx % I, o = idx / I;
    wT[(size_t)i * O + o] = w[idx];
}

// ---------------------------------------------------------------------------
// 1) Consolidated prep: masks + wpack x3 + ktab x3 + fcT x3 in ONE launch.
// ---------------------------------------------------------------------------
__global__ __launch_bounds__(256) void prep_k(
    const int* __restrict__ rm, unsigned long long* __restrict__ masks,
    const float* __restrict__ cw0, unsigned short* __restrict__ WP0,
    const float* __restrict__ cw1, unsigned short* __restrict__ WP1,
    const float* __restrict__ cw2, unsigned short* __restrict__ WP2,
    int* __restrict__ kt0, int* __restrict__ kt1, int* __restrict__ kt2,
    const float* __restrict__ fw0, float* __restrict__ W0T,
    const float* __restrict__ fw1, float* __restrict__ W1T,
    const float* __restrict__ fw2, float* __restrict__ W2T)
{
    const int b = blockIdx.x;
    const int t = threadIdx.x;
    if (b < 2) {
        int r = b * 256 + t;
        if (r < RR) {
            unsigned long long m = 0ull;
            #pragma unroll
            for (int k = 0; k < 64; ++k)
                if (rm[r * 64 + k]) m |= (1ull << k);
            masks[r] = m;
        }
    } else if (b < 258) {
        wpack_body(cw0, WP0, 64, 33, 25, 5, (b - 2) * 256 + t, 32 * 64 * 32);
    } else if (b < 546) {
        wpack_body(cw1, WP1, 128, 64, 9, 8, (b - 258) * 256 + t, 18 * 128 * 32);
    } else if (b < 1698) {
        wpack_body(cw2, WP2, 256, 128, 9, 16, (b - 546) * 256 + t, 36 * 256 * 32);
    } else if (b < 1699) {
        #pragma unroll
        for (int which = 0; which < 3; ++which) {
            int ngr, gpc, K, Wp, CL;
            int* dst;
            if (which == 0)      { ngr = 128; gpc = 5;  K = 5; Wp = 20; CL = 40;  dst = kt0; }
            else if (which == 1) { ngr = 72;  gpc = 8;  K = 3; Wp = 37; CL = 72;  dst = kt1; }
            else                 { ngr = 144; gpc = 16; K = 3; Wp = 19; CL = 136; dst = kt2; }
            if (t < ngr) {
                int shift = t / gpc;
                int off = 0;
                if (shift < K * K) {
                    int ky = shift / K, kx = shift % K;
                    off = (ky * Wp + kx) * CL + (t % gpc) * 8;
                }
                dst[t] = off;
            }
        }
    } else if (b < 2211) {
        fcT_body(fw0, W0T, 512, 256, (b - 1699) * 256 + t);
    } else if (b < 2723) {
        fcT_body(fw1, W1T, 256, 512, (b - 2211) * 256 + t);
    } else {
        fcT_body(fw2, W2T, 512, 256, (b - 2723) * 256 + t);
    }
}

// ---------------------------------------------------------------------------
// 2) Consolidated border zero for all three padded buffers in ONE launch.
// ---------------------------------------------------------------------------
__device__ __forceinline__ void border_body(
    unsigned short* __restrict__ base, int Hp, int Wp, int CPG, int pad,
    int sampleStride, int nborder, int idx, int total)
{
    if (idx >= total) return;
    int c8 = idx % CPG;
    int t  = idx / CPG;
    int bi = t % nborder;
    int nl = t / nborder;

    int topN = pad * Wp;
    int y, x;
    if (bi < topN) {
        y = bi / Wp; x = bi - y * Wp;
    } else if (bi < 2 * topN) {
        int b2 = bi - topN;
        y = Hp - pad + b2 / Wp; x = b2 % Wp;
    } else {
        int mid = bi - 2 * topN;
        int rowlen = 2 * pad;
        y = pad + mid / rowlen;
        int r = mid % rowlen;
        x = r < pad ? r : Wp - pad + (r - pad);
    }
    uint4 z = make_uint4(0, 0, 0, 0);
    *reinterpret_cast<uint4*>(
        &base[((size_t)nl * sampleStride) +
              ((size_t)y * Wp + x) * (CPG * 8) + c8 * 8]) = z;
}

__global__ __launch_bounds__(256) void border3_k(
    unsigned short* __restrict__ bufA, unsigned short* __restrict__ bufC,
    int A_SS, int C_SS, int nb1, int nb2, int Bc)
{
    int b = blockIdx.x;
    int t = threadIdx.x;
    if (b < nb1) {
        border_body(bufA, 76, 76, 5, 2, A_SS, 592, b * 256 + t, Bc * 592 * 5);
    } else if (b < nb2) {
        border_body(bufC, 37, 37, 8, 1, C_SS, 144, (b - nb1) * 256 + t,
                    Bc * 144 * 8);
    } else {
        border_body(bufC + 87616, 19, 19, 16, 1, C_SS, 72,
                    (b - nb2) * 256 + t, Bc * 72 * 16);
    }
}

// ---------------------------------------------------------------------------
// 3) Encode, banded HWC. v5: 512 threads (8 waves) + unroll-2 room walk.
// ---------------------------------------------------------------------------
__global__ __launch_bounds__(512) void encode_k(
    const int* __restrict__ X, const unsigned long long* __restrict__ masks,
    const float* __restrict__ emb, unsigned short* __restrict__ G,
    int n0, int sampleStride)
{
    __shared__ float tile[4][72][33];
    __shared__ unsigned s_pos[RR];
    __shared__ unsigned long long s_mask[RR];
    __shared__ unsigned short s_list[320];
    __shared__ float s_emb[64 * 33];
    __shared__ int s_woff[8];
    __shared__ int s_cnt;

    const int nl = blockIdx.x, band = blockIdx.y;
    const int by = band * 4;
    const int n  = n0 + nl;
    const int tid = threadIdx.x;

    float* tf = &tile[0][0][0];
    for (int i = tid; i < 4 * 72 * 33; i += 512) tf[i] = 0.0f;

    const int2* Xp = reinterpret_cast<const int2*>(X);
    bool hot = false;
    if (tid < RR) {
        int2 pos = Xp[n * RR + tid];
        s_pos[tid]  = (unsigned)pos.x | ((unsigned)pos.y << 16);
        s_mask[tid] = masks[tid];
        hot = (pos.y <= by + 3) && (pos.y + 7 >= by);
    }
    unsigned long long bal = __ballot(hot);
    if ((tid & 63) == 0) s_woff[tid >> 6] = (int)__popcll(bal);
    __syncthreads();
    if (tid == 0) {
        int acc = 0;
        #pragma unroll
        for (int w = 0; w < 8; ++w) { int c = s_woff[w]; s_woff[w] = acc; acc += c; }
        s_cnt = acc;
    }
    __syncthreads();
    if (hot) {
        int w = tid >> 6, b = tid & 63;
        unsigned long long before = (b == 0) ? 0ull : (bal & ((1ull << b) - 1ull));
        s_list[s_woff[w] + (int)__popcll(before)] = (unsigned short)tid;
    }
    __syncthreads();

    const int lane = tid & 63;
    const int wvi  = tid >> 6;          // 0..7
    const int dx   = lane >> 3;         // 0..7
    const int c0   = (lane & 7) * 5;    // channels [c0, c0+5) ∩ [0,33)
    const int cnt  = s_cnt;

    for (int base = 0; base < cnt; base += 64) {
        int cn = cnt - base; if (cn > 64) cn = 64;
        for (int i = tid; i < cn * 33; i += 512) {
            int hi = i / 33, cc = i - hi * 33;
            int r = s_list[base + hi];
            s_emb[i] = (cc == 0) ? 1.0f : emb[r * EMB + cc - 1];
        }
        __syncthreads();

        int j = wvi;
        for (; j + 8 < cn; j += 16) {
            int rA = s_list[base + j];
            int rB = s_list[base + j + 8];
            unsigned pA = s_pos[rA], pB = s_pos[rB];
            unsigned long long mA = s_mask[rA] >> (dx * 8);
            unsigned long long mB = s_mask[rB] >> (dx * 8);
            int xA = (pA & 0xffff) + dx, yA = pA >> 16;
            int xB = (pB & 0xffff) + dx, yB = pB >> 16;
            float eA[5], eB[5];
            #pragma unroll
            for (int q = 0; q < 5; ++q) {
                eA[q] = (c0 + q < 33) ? s_emb[j * 33 + c0 + q] : 0.0f;
                eB[q] = (c0 + q < 33) ? s_emb[(j + 8) * 33 + c0 + q] : 0.0f;
            }
            #pragma unroll
            for (int dyb = 0; dyb < 4; ++dyb) {
                int dA = by + dyb - yA;
                if ((unsigned)dA < 8u && ((mA >> dA) & 1ull)) {
                    #pragma unroll
                    for (int q = 0; q < 5; ++q)
                        if (c0 + q < 33)
                            atomicAdd(&tile[dyb][xA][c0 + q], eA[q]);
                }
                int dB = by + dyb - yB;
                if ((unsigned)dB < 8u && ((mB >> dB) & 1ull)) {
                    #pragma unroll
                    for (int q = 0; q < 5; ++q)
                        if (c0 + q < 33)
                            atomicAdd(&tile[dyb][xB][c0 + q], eB[q]);
                }
            }
        }
        for (; j < cn; j += 8) {
            int r = s_list[base + j];
            unsigned pxy = s_pos[r];
            int px = pxy & 0xffff, py = pxy >> 16;
            unsigned long long mm = s_mask[r] >> (dx * 8);
            int x = px + dx;
            float ev[5];
            #pragma unroll
            for (int q = 0; q < 5; ++q)
                ev[q] = (c0 + q < 33) ? s_emb[j * 33 + c0 + q] : 0.0f;
            #pragma unroll
            for (int dyb = 0; dyb < 4; ++dyb) {
                int dyr = by + dyb - py;
                if ((unsigned)dyr < 8u && ((mm >> dyr) & 1ull)) {
                    #pragma unroll
                    for (int q = 0; q < 5; ++q)
                        if (c0 + q < 33)
                            atomicAdd(&tile[dyb][x][c0 + q], ev[q]);
                }
            }
        }
        __syncthreads();
    }
    __syncthreads();

    unsigned short* Gn = G + (size_t)nl * sampleStride;
    for (int i = tid; i < 4 * 72 * 10; i += 512) {
        int cc = i % 10;
        int t  = i / 10;
        int x  = t % 72;
        int dyb = t / 72;
        int c0w = cc * 4;
        unsigned short r[4];
        #pragma unroll
        for (int j = 0; j < 4; ++j)
            r[j] = (c0w + j < 33) ? f2bf(tile[dyb][x][c0w + j]) : 0;
        uint2 pk;
        pk.x = (unsigned)r[0] | ((unsigned)r[1] << 16);
        pk.y = (unsigned)r[2] | ((unsigned)r[3] << 16);
        *reinterpret_cast<uint2*>(
            &Gn[((size_t)(by + dyb + 2) * 76 + (x + 2)) * 40 + c0w]) = pk;
    }
}

// ---------------------------------------------------------------------------
// 4a) conv0: 20x16-spatial-tile implicit-GEMM, bf16 MFMA 16x16x32.
//     Slab 24x20x40 = 38.4KB -> 4 blocks/CU (__launch_bounds__(256,4)).
//     y tiles {0,20,40,56}; y0=56 tile computes 4 garbage rows (stores
//     guarded; OOB slab reads land in bufC which follows bufA — harmless).
// ---------------------------------------------------------------------------
template<int KSTEPS>
__global__ __launch_bounds__(256, 4) void conv0_tile_k(
    const unsigned short* __restrict__ inP,   // [B][76][76][40] bf16
    const unsigned short* __restrict__ wPT,   // [KSTEPS][64][32] bf16
    const int* __restrict__ ktab,             // [KSTEPS*4] LDS offsets
    const float* __restrict__ bias,
    unsigned short* __restrict__ out,         // [B][5184][64] bf16
    int inSS, int outSS)
{
    constexpr int CL = 40;
    constexpr int LP = 72;
    __shared__ __align__(16) unsigned short slab[24 * 20 * CL];  // 38400 B
    __shared__ int s_kt[KSTEPS * 4];
    unsigned short* s_c = slab;

    const int tid = threadIdx.x;
    const int tl  = blockIdx.x;           // 0..19
    const int nl  = blockIdx.y;
    const int tyi = tl / 5, txi = tl % 5;
    const int y0 = tyi < 3 ? tyi * 20 : 56;
    const int x0 = txi < 4 ? txi * 16 : 56;

    const int lane = tid & 63, wv = tid >> 6, frow = lane & 15, fq = lane >> 4;

    if (tid < KSTEPS * 4) s_kt[tid] = ktab[tid];

    const unsigned short* in_n = inP + (size_t)nl * inSS;
    {
        const uint4* src = reinterpret_cast<const uint4*>(in_n);
        uint4* dst = reinterpret_cast<uint4*>(slab);
        #pragma unroll
        for (int it = 0; it < 10; ++it) {
            int q = tid + it * 256;
            if (q < 2400) {
                int r = q / 100, c = q - r * 100;
                dst[q] = src[((y0 + r) * 76 + x0) * 5 + c];
            }
        }
    }

    int ldsb[5];
    #pragma unroll
    for (int mf = 0; mf < 5; ++mf)
        ldsb[mf] = ((mf * 4 + wv) * 20 + frow) * CL;

    const unsigned short* wbase = wPT + (size_t)frow * 32 + fq * 8;

    f32x4 acc[5][4];
    #pragma unroll
    for (int a = 0; a < 5; ++a)
        #pragma unroll
        for (int b = 0; b < 4; ++b) acc[a][b] = (f32x4){0.f, 0.f, 0.f, 0.f};

    __syncthreads();

    #pragma unroll 2
    for (int kb = 0; kb < KSTEPS; ++kb) {
        int go = s_kt[kb * 4 + fq];
        bf16x8 af[5];
        #pragma unroll
        for (int mf = 0; mf < 5; ++mf)
            af[mf] = *reinterpret_cast<const bf16x8*>(&slab[ldsb[mf] + go]);
        const unsigned short* wk = wbase + (size_t)kb * 64 * 32;
        #pragma unroll
        for (int ng = 0; ng < 4; ++ng) {
            bf16x8 bf = *reinterpret_cast<const bf16x8*>(wk + ng * 16 * 32);
            #pragma unroll
            for (int mf = 0; mf < 5; ++mf)
                acc[mf][ng] = __builtin_amdgcn_mfma_f32_16x16x32_bf16(
                    af[mf], bf, acc[mf][ng], 0, 0, 0);
        }
    }

    unsigned short* out_n = out + (size_t)nl * outSS;
    const int erow = tid >> 2, eseg = tid & 3;
    #pragma unroll
    for (int mf = 0; mf < 5; ++mf) {
        __syncthreads();
        #pragma unroll
        for (int ng = 0; ng < 4; ++ng) {
            float bv = bias[ng * 16 + frow];
            #pragma unroll
            for (int j = 0; j < 4; ++j)
                s_c[(wv * 16 + fq * 4 + j) * LP + ng * 16 + frow] =
                    f2bf(fmaxf(acc[mf][ng][j] + bv, 0.0f));
        }
        __syncthreads();
        {
            int ty = mf * 4 + (erow >> 4);
            int tx = erow & 15;
            if (y0 + ty < 72) {
                int pos = (y0 + ty) * 72 + (x0 + tx);
                ushort8 v0 = *reinterpret_cast<const ushort8*>(
                    &s_c[erow * LP + eseg * 16]);
                ushort8 v1 = *reinterpret_cast<const ushort8*>(
                    &s_c[erow * LP + eseg * 16 + 8]);
                unsigned short* op = out_n + (size_t)pos * 64 + eseg * 16;
                *reinterpret_cast<ushort8*>(op) = v0;
                *reinterpret_cast<ushort8*>(op + 8) = v1;
            }
        }
    }
}

// ---------------------------------------------------------------------------
// 4b) Generic row-slab implicit-GEMM conv (conv1/conv2), bf16 MFMA 16x16x32.
// ---------------------------------------------------------------------------
template<int MFRAG, int NG, int KH, int CPG, int CL, int SLAB, int KSTEPS>
__global__ __launch_bounds__(256, 2) void conv_mfma_k(
    const unsigned short* __restrict__ inP,
    const unsigned short* __restrict__ wPT,
    const int* __restrict__ ktab,
    const float* __restrict__ bias,
    unsigned short* __restrict__ out,
    int W, int Wp, int Mtot, int inSS, int outSS, int COUT)
{
    constexpr int Mblk = MFRAG * 64;
    constexpr int NOC  = NG * 16;
    constexpr int SEGS = NOC / 16;
    constexpr int LP   = NOC + 8;
    constexpr int CP   = CPG * 8;
    constexpr int SMEM = (SLAB * 2 > 64 * LP * 2) ? SLAB * 2 : 64 * LP * 2;
    __shared__ __align__(16) char smem[SMEM];
    __shared__ int s_kt[KSTEPS * 4];
    unsigned short* slab = reinterpret_cast<unsigned short*>(smem);
    unsigned short* s_c  = reinterpret_cast<unsigned short*>(smem);

    const int tid  = threadIdx.x;
    const int mb   = blockIdx.x;
    const int ocb  = blockIdx.y;
    const int nl   = blockIdx.z;
    const int lane = tid & 63;
    const int wv   = tid >> 6;
    const int frow = lane & 15;
    const int fq   = lane >> 4;

    if (tid < KSTEPS * 4) s_kt[tid] = ktab[tid];

    const int p0    = mb * Mblk;
    const int y0    = p0 / W;
    const int plast = (p0 + Mblk < Mtot ? p0 + Mblk : Mtot) - 1;
    const int rows  = plast / W - y0 + KH;

    const unsigned short* in_n =
        inP + (size_t)nl * inSS + (size_t)y0 * Wp * CP;
    const int nchunks = rows * Wp * CPG;
    for (int q = tid; q < nchunks; q += 256) {
        int pix = q / CPG, c8 = q - pix * CPG;
        uint4 v = reinterpret_cast<const uint4*>(in_n)[q];
        *reinterpret_cast<uint4*>(&slab[pix * CL + c8 * 8]) = v;
    }

    int ldsb[MFRAG];
    #pragma unroll
    for (int mf = 0; mf < MFRAG; ++mf) {
        int p  = p0 + mf * 64 + wv * 16 + frow;
        int pc = p < Mtot ? p : (Mtot - 1);
        int y  = pc / W;
        int x  = pc - y * W;
        ldsb[mf] = ((y - y0) * Wp + x) * CL;
    }
    const unsigned short* wbase =
        wPT + ((size_t)(ocb * NOC + frow)) * 32 + fq * 8;

    f32x4 acc[MFRAG][NG];
    #pragma unroll
    for (int mf = 0; mf < MFRAG; ++mf)
        #pragma unroll
        for (int ng = 0; ng < NG; ++ng)
            acc[mf][ng] = (f32x4){0.f, 0.f, 0.f, 0.f};

    __syncthreads();

    for (int kb = 0; kb < KSTEPS; ++kb) {
        int go = s_kt[kb * 4 + fq];
        bf16x8 af[MFRAG];
        #pragma unroll
        for (int mf = 0; mf < MFRAG; ++mf)
            af[mf] = *reinterpret_cast<const bf16x8*>(&slab[ldsb[mf] + go]);
        const unsigned short* wk = wbase + (size_t)kb * COUT * 32;
        #pragma unroll
        for (int ng = 0; ng < NG; ++ng) {
            bf16x8 bf = *reinterpret_cast<const bf16x8*>(wk + ng * 16 * 32);
            #pragma unroll
            for (int mf = 0; mf < MFRAG; ++mf)
                acc[mf][ng] = __builtin_amdgcn_mfma_f32_16x16x32_bf16(
                    af[mf], bf, acc[mf][ng], 0, 0, 0);
        }
    }

    unsigned short* out_n = out + (size_t)nl * outSS;
    #pragma unroll
    for (int mf = 0; mf < MFRAG; ++mf) {
        __syncthreads();
        #pragma unroll
        for (int ng = 0; ng < NG; ++ng) {
            float bv = bias[ocb * NOC + ng * 16 + frow];
            #pragma unroll
            for (int j = 0; j < 4; ++j)
                s_c[(wv * 16 + fq * 4 + j) * LP + ng * 16 + frow] =
                    f2bf(fmaxf(acc[mf][ng][j] + bv, 0.0f));
        }
        __syncthreads();
        for (int t = tid; t < 64 * SEGS; t += 256) {
            int row = t / SEGS, seg = t % SEGS;
            int p = p0 + mf * 64 + row;
            if (p < Mtot) {
                ushort8 v0 = *reinterpret_cast<const ushort8*>(
                    &s_c[row * LP + seg * 16]);
                ushort8 v1 = *reinterpret_cast<const ushort8*>(
                    &s_c[row * LP + seg * 16 + 8]);
                unsigned short* op =
                    out_n + (size_t)p * COUT + ocb * NOC + seg * 16;
                *reinterpret_cast<ushort8*>(op) = v0;
                *reinterpret_cast<ushort8*>(op + 8) = v1;
            }
        }
    }
}

// ---------------------------------------------------------------------------
// 5) MaxPool 3x3 s2 VALID, HWC, ushort8 (post-ReLU: u16 max).
// ---------------------------------------------------------------------------
__global__ __launch_bounds__(256) void pool_k(
    const unsigned short* __restrict__ in, unsigned short* __restrict__ out,
    int CG, int C, int W, int inSS,
    int HO, int WO, int Wpo, int outSS, int total)
{
    int idx = blockIdx.x * 256 + threadIdx.x;
    if (idx >= total) return;
    int cg = idx % CG;
    int t  = idx / CG;
    int x  = t % WO;
    t /= WO;
    int y  = t % HO;
    int nl = t / HO;

    const unsigned short* pin = in + (size_t)nl * inSS + cg * 8;
    ushort8 mx = {0,0,0,0,0,0,0,0};
    #pragma unroll
    for (int dy = 0; dy < 3; ++dy)
        #pragma unroll
        for (int dx = 0; dx < 3; ++dx) {
            ushort8 v = *reinterpret_cast<const ushort8*>(
                pin + ((size_t)(2 * y + dy) * W + (2 * x + dx)) * C);
            #pragma unroll
            for (int j = 0; j < 8; ++j) mx[j] = v[j] > mx[j] ? v[j] : mx[j];
        }
    *reinterpret_cast<ushort8*>(
        out + (size_t)nl * outSS +
        ((size_t)(y + 1) * Wpo + (x + 1)) * C + cg * 8) = mx;
}

// ---------------------------------------------------------------------------
// 6) Fused pool2 (3x3 s2 on [17][17][256]) + global average pool -> fp32
// ---------------------------------------------------------------------------
__global__ __launch_bounds__(512) void pool2gap_k(
    const unsigned short* __restrict__ in, float* __restrict__ out,
    int inSS, int n0)
{
    __shared__ float part[256];
    const int nl = blockIdx.x;
    const int c    = threadIdx.x & 255;
    const int half = threadIdx.x >> 8;
    const unsigned short* p = in + (size_t)nl * inSS + c;
    float s = 0.0f;
    for (int w = half * 32; w < half * 32 + 32; ++w) {
        int y = w >> 3, x = w & 7;
        unsigned short mx = 0;
        #pragma unroll
        for (int dy = 0; dy < 3; ++dy)
            #pragma unroll
            for (int dx = 0; dx < 3; ++dx) {
                unsigned short v = p[((size_t)(2*y+dy) * 17 + (2*x+dx)) * 256];
                mx = v > mx ? v : mx;
            }
        s += bf2f(mx);
    }
    if (half) part[c] = s;
    __syncthreads();
    if (!half) out[(size_t)(n0 + nl) * 256 + c] = (s + part[c]) * (1.0f / 64.0f);
}

// ---------------------------------------------------------------------------
// 7) Fused 3-layer FC head (256->512->256->512), one block per sample
// ---------------------------------------------------------------------------
__global__ __launch_bounds__(256) void fc_fused_k(
    const float* __restrict__ in,
    const float* __restrict__ w0T, const float* __restrict__ b0,
    const float* __restrict__ w1T, const float* __restrict__ b1,
    const float* __restrict__ w2T, const float* __restrict__ b2,
    float* __restrict__ out)
{
    __shared__ float s_in[256], s_h0[512], s_h1[256];
    const int n = blockIdx.x, t = threadIdx.x;
    s_in[t] = in[(size_t)n * 256 + t];
    __syncthreads();
    float a0 = 0.f, a1 = 0.f;
    for (int i = 0; i < 256; ++i) {
        float v = s_in[i];
        a0 += v * w0T[i * 512 + t];
        a1 += v * w0T[i * 512 + t + 256];
    }
    s_h0[t]       = fmaxf(a0 + b0[t], 0.0f);
    s_h0[t + 256] = fmaxf(a1 + b0[t + 256], 0.0f);
    __syncthreads();
    float h = 0.f;
    for (int i = 0; i < 512; ++i) h += s_h0[i] * w1T[i * 256 + t];
    s_h1[t] = fmaxf(h + b1[t], 0.0f);
    __syncthreads();
    a0 = 0.f; a1 = 0.f;
    for (int i = 0; i < 256; ++i) {
        float v = s_h1[i];
        a0 += v * w2T[i * 512 + t];
        a1 += v * w2T[i * 512 + t + 256];
    }
    out[(size_t)n * 512 + t]       = a0 + b2[t];
    out[(size_t)n * 512 + t + 256] = a1 + b2[t + 256];
}

// ---------------------------------------------------------------------------
// Launch. 10 kernels/call.
// ---------------------------------------------------------------------------
extern "C" void kernel_launch(void* const* d_in, const int* in_sizes, int n_in,
                              void* d_out, int out_size, void* d_ws, size_t ws_size,
                              hipStream_t stream)
{
    const int*   X   = (const int*)d_in[0];
    const int*   rm  = (const int*)d_in[1];
    const float* emb = (const float*)d_in[2];
    const float* cw0 = (const float*)d_in[3];
    const float* cb0 = (const float*)d_in[4];
    const float* cw1 = (const float*)d_in[5];
    const float* cb1 = (const float*)d_in[6];
    const float* cw2 = (const float*)d_in[7];
    const float* cb2 = (const float*)d_in[8];
    const float* fw0 = (const float*)d_in[9];
    const float* fb0 = (const float*)d_in[10];
    const float* fw1 = (const float*)d_in[11];
    const float* fb1 = (const float*)d_in[12];
    const float* fw2 = (const float*)d_in[13];
    const float* fb2 = (const float*)d_in[14];
    float* out = (float*)d_out;

    char* p = (char*)d_ws;
    auto alloc = [&](size_t bytes) -> char* {
        char* r = p; p += (bytes + 255) & ~(size_t)255; return r;
    };
    unsigned short* WP0 = (unsigned short*)alloc((size_t)32 * 64 * 32 * 2);
    unsigned short* WP1 = (unsigned short*)alloc((size_t)18 * 128 * 32 * 2);
    unsigned short* WP2 = (unsigned short*)alloc((size_t)36 * 256 * 32 * 2);
    int* KT0 = (int*)alloc(128 * 4);
    int* KT1 = (int*)alloc(72 * 4);
    int* KT2 = (int*)alloc(144 * 4);
    unsigned long long* MASKS = (unsigned long long*)alloc(RR * 8);
    float* W0T  = (float*)alloc((size_t)256 * 512 * 4);
    float* W1T  = (float*)alloc((size_t)512 * 256 * 4);
    float* W2T  = (float*)alloc((size_t)256 * 512 * 4);
    float* GAPB = (float*)alloc((size_t)NB * 256 * 4);
    size_t fixed_bytes = (size_t)(p - (char*)d_ws);

    const size_t A_FL = 231040, B_FL = 331776, C_FL = 133824;   // u16
    const size_t per_sample = (A_FL + B_FL + C_FL) * 2 + 768;
    int Bc = 128;
    while (Bc > 1 && fixed_bytes + (size_t)Bc * per_sample > ws_size) Bc >>= 1;

    unsigned short* bufA = (unsigned short*)alloc((size_t)Bc * A_FL * 2);
    unsigned short* bufC = (unsigned short*)alloc((size_t)Bc * C_FL * 2);
    unsigned short* bufB = (unsigned short*)alloc((size_t)Bc * B_FL * 2);

    // ---- consolidated prep (1 launch) ----
    prep_k<<<3235, 256, 0, stream>>>(
        rm, MASKS, cw0, WP0, cw1, WP1, cw2, WP2,
        KT0, KT1, KT2, fw0, W0T, fw1, W1T, fw2, W2T);

    // ---- chunked pipeline ----
    for (int n0 = 0; n0 < NB; n0 += Bc) {
        int nb1 = (Bc * 592 * 5 + 255) / 256;
        int nbc1 = (Bc * 144 * 8 + 255) / 256;
        int nbc2 = (Bc * 72 * 16 + 255) / 256;
        border3_k<<<nb1 + nbc1 + nbc2, 256, 0, stream>>>(
            bufA, bufC, (int)A_FL, (int)C_FL, nb1, nb1 + nbc1, Bc);

        // encode -> A (HWC G [76][76][40], interior +2)
        encode_k<<<dim3(Bc, 18), 512, 0, stream>>>(X, MASKS, emb, bufA, n0, (int)A_FL);

        // conv0: A -> B  (20 20x16 tiles/sample, COUT=64, 32 ksteps)
        conv0_tile_k<32><<<dim3(20, Bc), 256, 0, stream>>>(
            bufA, WP0, KT0, cb0, bufB, (int)A_FL, (int)B_FL);
        // pool0: B [72][72][64] -> C P0p [37][37][64] interior +1
        pool_k<<<(Bc * 35 * 35 * 8 + 255) / 256, 256, 0, stream>>>(
            bufB, bufC, 8, 64, 72, (int)B_FL,
            35, 35, 37, (int)C_FL, Bc * 35 * 35 * 8);

        // conv1: C -> A  (M=1225, Mblk=256 -> 5 mblocks, COUT=128)
        conv_mfma_k<4, 8, 3, 8, 72, 29304, 18><<<dim3(5, 1, Bc), 256, 0, stream>>>(
            bufC, WP1, KT1, cb1, bufA, 35, 37,
            1225, (int)C_FL, (int)A_FL, 128);
        // pool1: A [35][35][128] -> C+87616 P1p [19][19][128] interior +1
        pool_k<<<(Bc * 17 * 17 * 16 + 255) / 256, 256, 0, stream>>>(
            bufA, bufC + 87616, 16, 128, 35, (int)A_FL,
            17, 17, 19, (int)C_FL, Bc * 17 * 17 * 16);

        // conv2: C+87616 -> B  (M=289, Mblk=128 -> 3 mblocks, 2 oc-blocks)
        conv_mfma_k<2, 8, 3, 16, 136, 28424, 36><<<dim3(3, 2, Bc), 256, 0, stream>>>(
            bufC + 87616, WP2, KT2, cb2, bufB, 17, 19,
            289, (int)C_FL, (int)B_FL, 256);

        // fused pool2 + GAP: B [17][17][256] -> GAPB fp32
        pool2gap_k<<<Bc, 512, 0, stream>>>(bufB, GAPB, (int)B_FL, n0);
    }

    // fused FC head
    fc_fused_k<<<NB, 256, 0, stream>>>(GAPB, W0T, fb0, W1T, fb1, W2T, fb2, out);
}

// Round 16
// 500.026 us; speedup vs baseline: 1.0382x; 1.0382x over previous
//
#include <hip/hip_runtime.h>
#include <hip/hip_bf16.h>
#include <cstdint>
#include <cstddef>

#define NB      128
#define RR      300
#define EMB     32

typedef __bf16 bf16x8 __attribute__((ext_vector_type(8)));
typedef float  f32x4  __attribute__((ext_vector_type(4)));
typedef unsigned short ushort8 __attribute__((ext_vector_type(8)));

__device__ __forceinline__ unsigned short f2bf(float f) {
    union { __hip_bfloat16 h; unsigned short u; } c;
    c.h = __float2bfloat16(f);
    return c.u;
}
__device__ __forceinline__ float bf2f(unsigned short u) {
    union { __hip_bfloat16 h; unsigned short u; } c;
    c.u = u;
    return __bfloat162float(c.h);
}

// ---------------------------------------------------------------------------
// helpers for the consolidated prep kernel
// ---------------------------------------------------------------------------
__device__ __forceinline__ void wpack_body(
    const float* __restrict__ w, unsigned short* __restrict__ wPT,
    int COUT, int CIN, int KK, int gpc, int idx, int total)
{
    if (idx >= total) return;
    int kk = idx & 31;
    int t  = idx >> 5;
    int oc = t % COUT;
    int kb = t / COUT;
    int g  = kb * 4 + (kk >> 3);
    int j  = kk & 7;
    int shift = g / gpc;
    int ci    = (g % gpc) * 8 + j;
    float v = (shift < KK && ci < CIN)
        ? w[(size_t)oc * CIN * KK + (size_t)ci * KK + shift] : 0.0f;
    wPT[idx] = f2bf(v);
}

__device__ __forceinline__ void fcT_body(
    const float* __restrict__ w, float* __restrict__ wT, int O, int I, int idx)
{
    if (idx >= O * I) return;
    int i = idx % I, o = idx / I;
    wT[(size_t)i * O + o] = w[idx];
}

// ---------------------------------------------------------------------------
// 1) Consolidated prep: masks + wpack x3 + ktab x3 + fcT x3 in ONE launch.
// ---------------------------------------------------------------------------
__global__ __launch_bounds__(256) void prep_k(
    const int* __restrict__ rm, unsigned long long* __restrict__ masks,
    const float* __restrict__ cw0, unsigned short* __restrict__ WP0,
    const float* __restrict__ cw1, unsigned short* __restrict__ WP1,
    const float* __restrict__ cw2, unsigned short* __restrict__ WP2,
    int* __restrict__ kt0, int* __restrict__ kt1, int* __restrict__ kt2,
    const float* __restrict__ fw0, float* __restrict__ W0T,
    const float* __restrict__ fw1, float* __restrict__ W1T,
    const float* __restrict__ fw2, float* __restrict__ W2T)
{
    const int b = blockIdx.x;
    const int t = threadIdx.x;
    if (b < 2) {
        int r = b * 256 + t;
        if (r < RR) {
            unsigned long long m = 0ull;
            #pragma unroll
            for (int k = 0; k < 64; ++k)
                if (rm[r * 64 + k]) m |= (1ull << k);
            masks[r] = m;
        }
    } else if (b < 258) {
        wpack_body(cw0, WP0, 64, 33, 25, 5, (b - 2) * 256 + t, 32 * 64 * 32);
    } else if (b < 546) {
        wpack_body(cw1, WP1, 128, 64, 9, 8, (b - 258) * 256 + t, 18 * 128 * 32);
    } else if (b < 1698) {
        wpack_body(cw2, WP2, 256, 128, 9, 16, (b - 546) * 256 + t, 36 * 256 * 32);
    } else if (b < 1699) {
        #pragma unroll
        for (int which = 0; which < 3; ++which) {
            int ngr, gpc, K, Wp, CL;
            int* dst;
            if (which == 0)      { ngr = 128; gpc = 5;  K = 5; Wp = 20; CL = 40;  dst = kt0; }
            else if (which == 1) { ngr = 72;  gpc = 8;  K = 3; Wp = 37; CL = 72;  dst = kt1; }
            else                 { ngr = 144; gpc = 16; K = 3; Wp = 19; CL = 136; dst = kt2; }
            if (t < ngr) {
                int shift = t / gpc;
                int off = 0;
                if (shift < K * K) {
                    int ky = shift / K, kx = shift % K;
                    off = (ky * Wp + kx) * CL + (t % gpc) * 8;
                }
                dst[t] = off;
            }
        }
    } else if (b < 2211) {
        fcT_body(fw0, W0T, 512, 256, (b - 1699) * 256 + t);
    } else if (b < 2723) {
        fcT_body(fw1, W1T, 256, 512, (b - 2211) * 256 + t);
    } else {
        fcT_body(fw2, W2T, 512, 256, (b - 2723) * 256 + t);
    }
}

// ---------------------------------------------------------------------------
// 2) Consolidated border zero for all three padded buffers in ONE launch.
// ---------------------------------------------------------------------------
__device__ __forceinline__ void border_body(
    unsigned short* __restrict__ base, int Hp, int Wp, int CPG, int pad,
    int sampleStride, int nborder, int idx, int total)
{
    if (idx >= total) return;
    int c8 = idx % CPG;
    int t  = idx / CPG;
    int bi = t % nborder;
    int nl = t / nborder;

    int topN = pad * Wp;
    int y, x;
    if (bi < topN) {
        y = bi / Wp; x = bi - y * Wp;
    } else if (bi < 2 * topN) {
        int b2 = bi - topN;
        y = Hp - pad + b2 / Wp; x = b2 % Wp;
    } else {
        int mid = bi - 2 * topN;
        int rowlen = 2 * pad;
        y = pad + mid / rowlen;
        int r = mid % rowlen;
        x = r < pad ? r : Wp - pad + (r - pad);
    }
    uint4 z = make_uint4(0, 0, 0, 0);
    *reinterpret_cast<uint4*>(
        &base[((size_t)nl * sampleStride) +
              ((size_t)y * Wp + x) * (CPG * 8) + c8 * 8]) = z;
}

__global__ __launch_bounds__(256) void border3_k(
    unsigned short* __restrict__ bufA, unsigned short* __restrict__ bufC,
    int A_SS, int C_SS, int nb1, int nb2, int Bc)
{
    int b = blockIdx.x;
    int t = threadIdx.x;
    if (b < nb1) {
        border_body(bufA, 76, 76, 5, 2, A_SS, 592, b * 256 + t, Bc * 592 * 5);
    } else if (b < nb2) {
        border_body(bufC, 37, 37, 8, 1, C_SS, 144, (b - nb1) * 256 + t,
                    Bc * 144 * 8);
    } else {
        border_body(bufC + 87616, 19, 19, 16, 1, C_SS, 72,
                    (b - nb2) * 256 + t, Bc * 72 * 16);
    }
}

// ---------------------------------------------------------------------------
// 3) Encode, banded HWC. v5: 512 threads (8 waves) + unroll-2 room walk.
// ---------------------------------------------------------------------------
__global__ __launch_bounds__(512) void encode_k(
    const int* __restrict__ X, const unsigned long long* __restrict__ masks,
    const float* __restrict__ emb, unsigned short* __restrict__ G,
    int n0, int sampleStride)
{
    __shared__ float tile[4][72][33];
    __shared__ unsigned s_pos[RR];
    __shared__ unsigned long long s_mask[RR];
    __shared__ unsigned short s_list[320];
    __shared__ float s_emb[64 * 33];
    __shared__ int s_woff[8];
    __shared__ int s_cnt;

    const int nl = blockIdx.x, band = blockIdx.y;
    const int by = band * 4;
    const int n  = n0 + nl;
    const int tid = threadIdx.x;

    float* tf = &tile[0][0][0];
    for (int i = tid; i < 4 * 72 * 33; i += 512) tf[i] = 0.0f;

    const int2* Xp = reinterpret_cast<const int2*>(X);
    bool hot = false;
    if (tid < RR) {
        int2 pos = Xp[n * RR + tid];
        s_pos[tid]  = (unsigned)pos.x | ((unsigned)pos.y << 16);
        s_mask[tid] = masks[tid];
        hot = (pos.y <= by + 3) && (pos.y + 7 >= by);
    }
    unsigned long long bal = __ballot(hot);
    if ((tid & 63) == 0) s_woff[tid >> 6] = (int)__popcll(bal);
    __syncthreads();
    if (tid == 0) {
        int acc = 0;
        #pragma unroll
        for (int w = 0; w < 8; ++w) { int c = s_woff[w]; s_woff[w] = acc; acc += c; }
        s_cnt = acc;
    }
    __syncthreads();
    if (hot) {
        int w = tid >> 6, b = tid & 63;
        unsigned long long before = (b == 0) ? 0ull : (bal & ((1ull << b) - 1ull));
        s_list[s_woff[w] + (int)__popcll(before)] = (unsigned short)tid;
    }
    __syncthreads();

    const int lane = tid & 63;
    const int wvi  = tid >> 6;          // 0..7
    const int dx   = lane >> 3;         // 0..7
    const int c0   = (lane & 7) * 5;    // channels [c0, c0+5) ∩ [0,33)
    const int cnt  = s_cnt;

    for (int base = 0; base < cnt; base += 64) {
        int cn = cnt - base; if (cn > 64) cn = 64;
        for (int i = tid; i < cn * 33; i += 512) {
            int hi = i / 33, cc = i - hi * 33;
            int r = s_list[base + hi];
            s_emb[i] = (cc == 0) ? 1.0f : emb[r * EMB + cc - 1];
        }
        __syncthreads();

        int j = wvi;
        for (; j + 8 < cn; j += 16) {
            int rA = s_list[base + j];
            int rB = s_list[base + j + 8];
            unsigned pA = s_pos[rA], pB = s_pos[rB];
            unsigned long long mA = s_mask[rA] >> (dx * 8);
            unsigned long long mB = s_mask[rB] >> (dx * 8);
            int xA = (pA & 0xffff) + dx, yA = pA >> 16;
            int xB = (pB & 0xffff) + dx, yB = pB >> 16;
            float eA[5], eB[5];
            #pragma unroll
            for (int q = 0; q < 5; ++q) {
                eA[q] = (c0 + q < 33) ? s_emb[j * 33 + c0 + q] : 0.0f;
                eB[q] = (c0 + q < 33) ? s_emb[(j + 8) * 33 + c0 + q] : 0.0f;
            }
            #pragma unroll
            for (int dyb = 0; dyb < 4; ++dyb) {
                int dA = by + dyb - yA;
                if ((unsigned)dA < 8u && ((mA >> dA) & 1ull)) {
                    #pragma unroll
                    for (int q = 0; q < 5; ++q)
                        if (c0 + q < 33)
                            atomicAdd(&tile[dyb][xA][c0 + q], eA[q]);
                }
                int dB = by + dyb - yB;
                if ((unsigned)dB < 8u && ((mB >> dB) & 1ull)) {
                    #pragma unroll
                    for (int q = 0; q < 5; ++q)
                        if (c0 + q < 33)
                            atomicAdd(&tile[dyb][xB][c0 + q], eB[q]);
                }
            }
        }
        for (; j < cn; j += 8) {
            int r = s_list[base + j];
            unsigned pxy = s_pos[r];
            int px = pxy & 0xffff, py = pxy >> 16;
            unsigned long long mm = s_mask[r] >> (dx * 8);
            int x = px + dx;
            float ev[5];
            #pragma unroll
            for (int q = 0; q < 5; ++q)
                ev[q] = (c0 + q < 33) ? s_emb[j * 33 + c0 + q] : 0.0f;
            #pragma unroll
            for (int dyb = 0; dyb < 4; ++dyb) {
                int dyr = by + dyb - py;
                if ((unsigned)dyr < 8u && ((mm >> dyr) & 1ull)) {
                    #pragma unroll
                    for (int q = 0; q < 5; ++q)
                        if (c0 + q < 33)
                            atomicAdd(&tile[dyb][x][c0 + q], ev[q]);
                }
            }
        }
        __syncthreads();
    }
    __syncthreads();

    unsigned short* Gn = G + (size_t)nl * sampleStride;
    for (int i = tid; i < 4 * 72 * 10; i += 512) {
        int cc = i % 10;
        int t  = i / 10;
        int x  = t % 72;
        int dyb = t / 72;
        int c0w = cc * 4;
        unsigned short r[4];
        #pragma unroll
        for (int j = 0; j < 4; ++j)
            r[j] = (c0w + j < 33) ? f2bf(tile[dyb][x][c0w + j]) : 0;
        uint2 pk;
        pk.x = (unsigned)r[0] | ((unsigned)r[1] << 16);
        pk.y = (unsigned)r[2] | ((unsigned)r[3] << 16);
        *reinterpret_cast<uint2*>(
            &Gn[((size_t)(by + dyb + 2) * 76 + (x + 2)) * 40 + c0w]) = pk;
    }
}

// ---------------------------------------------------------------------------
// 4a) conv0: 24x16-spatial-tile implicit-GEMM, bf16 MFMA 16x16x32.
//     Round-14 shape (proven 104 µs) + B-fragment software prefetch:
//     load kb+1's weight fragments before issuing kb's MFMAs.
// ---------------------------------------------------------------------------
template<int KSTEPS>
__global__ __launch_bounds__(256, 3) void conv0_tile_k(
    const unsigned short* __restrict__ inP,   // [B][76][76][40] bf16
    const unsigned short* __restrict__ wPT,   // [KSTEPS][64][32] bf16
    const int* __restrict__ ktab,             // [KSTEPS*4] LDS offsets
    const float* __restrict__ bias,
    unsigned short* __restrict__ out,         // [B][5184][64] bf16
    int inSS, int outSS)
{
    constexpr int CL = 40;
    constexpr int LP = 72;
    __shared__ __align__(16) unsigned short slab[28 * 20 * CL];  // 44800 B
    __shared__ int s_kt[KSTEPS * 4];
    unsigned short* s_c = slab;

    const int tid = threadIdx.x;
    const int tl  = blockIdx.x;           // 0..14
    const int nl  = blockIdx.y;
    const int tyi = tl / 5, txi = tl % 5;
    const int y0 = tyi * 24;
    const int x0 = txi < 4 ? txi * 16 : 56;

    const int lane = tid & 63, wv = tid >> 6, frow = lane & 15, fq = lane >> 4;

    if (tid < KSTEPS * 4) s_kt[tid] = ktab[tid];

    const unsigned short* in_n = inP + (size_t)nl * inSS;
    {
        const uint4* src = reinterpret_cast<const uint4*>(in_n);
        uint4* dst = reinterpret_cast<uint4*>(slab);
        #pragma unroll
        for (int it = 0; it < 11; ++it) {
            int q = tid + it * 256;
            if (q < 2800) {
                int r = q / 100, c = q - r * 100;
                dst[q] = src[((y0 + r) * 76 + x0) * 5 + c];
            }
        }
    }

    int ldsb[6];
    #pragma unroll
    for (int mf = 0; mf < 6; ++mf)
        ldsb[mf] = ((mf * 4 + wv) * 20 + frow) * CL;

    const unsigned short* wbase = wPT + (size_t)frow * 32 + fq * 8;

    f32x4 acc[6][4];
    #pragma unroll
    for (int a = 0; a < 6; ++a)
        #pragma unroll
        for (int b = 0; b < 4; ++b) acc[a][b] = (f32x4){0.f, 0.f, 0.f, 0.f};

    // prefetch B fragments for kb=0 (before barrier: global loads, no LDS dep)
    ushort8 bcur[4];
    #pragma unroll
    for (int ng = 0; ng < 4; ++ng)
        bcur[ng] = *reinterpret_cast<const ushort8*>(wbase + ng * 16 * 32);

    __syncthreads();

    for (int kb = 0; kb < KSTEPS; ++kb) {
        int go = s_kt[kb * 4 + fq];
        bf16x8 af[6];
        #pragma unroll
        for (int mf = 0; mf < 6; ++mf)
            af[mf] = *reinterpret_cast<const bf16x8*>(&slab[ldsb[mf] + go]);
        // prefetch next k-step's B fragments
        ushort8 bnext[4];
        if (kb + 1 < KSTEPS) {
            const unsigned short* wk1 = wbase + (size_t)(kb + 1) * 64 * 32;
            #pragma unroll
            for (int ng = 0; ng < 4; ++ng)
                bnext[ng] = *reinterpret_cast<const ushort8*>(wk1 + ng * 16 * 32);
        }
        #pragma unroll
        for (int ng = 0; ng < 4; ++ng) {
            union { ushort8 u; bf16x8 b; } cv;
            cv.u = bcur[ng];
            #pragma unroll
            for (int mf = 0; mf < 6; ++mf)
                acc[mf][ng] = __builtin_amdgcn_mfma_f32_16x16x32_bf16(
                    af[mf], cv.b, acc[mf][ng], 0, 0, 0);
        }
        #pragma unroll
        for (int ng = 0; ng < 4; ++ng) bcur[ng] = bnext[ng];
    }

    unsigned short* out_n = out + (size_t)nl * outSS;
    const int erow = tid >> 2, eseg = tid & 3;
    #pragma unroll
    for (int mf = 0; mf < 6; ++mf) {
        __syncthreads();
        #pragma unroll
        for (int ng = 0; ng < 4; ++ng) {
            float bv = bias[ng * 16 + frow];
            #pragma unroll
            for (int j = 0; j < 4; ++j)
                s_c[(wv * 16 + fq * 4 + j) * LP + ng * 16 + frow] =
                    f2bf(fmaxf(acc[mf][ng][j] + bv, 0.0f));
        }
        __syncthreads();
        {
            int ty = mf * 4 + (erow >> 4);
            int tx = erow & 15;
            int pos = (y0 + ty) * 72 + (x0 + tx);
            ushort8 v0 = *reinterpret_cast<const ushort8*>(
                &s_c[erow * LP + eseg * 16]);
            ushort8 v1 = *reinterpret_cast<const ushort8*>(
                &s_c[erow * LP + eseg * 16 + 8]);
            unsigned short* op = out_n + (size_t)pos * 64 + eseg * 16;
            *reinterpret_cast<ushort8*>(op) = v0;
            *reinterpret_cast<ushort8*>(op + 8) = v1;
        }
    }
}

// ---------------------------------------------------------------------------
// 4b) Generic row-slab implicit-GEMM conv (conv1/conv2), bf16 MFMA 16x16x32.
// ---------------------------------------------------------------------------
template<int MFRAG, int NG, int KH, int CPG, int CL, int SLAB, int KSTEPS>
__global__ __launch_bounds__(256, 2) void conv_mfma_k(
    const unsigned short* __restrict__ inP,
    const unsigned short* __restrict__ wPT,
    const int* __restrict__ ktab,
    const float* __restrict__ bias,
    unsigned short* __restrict__ out,
    int W, int Wp, int Mtot, int inSS, int outSS, int COUT)
{
    constexpr int Mblk = MFRAG * 64;
    constexpr int NOC  = NG * 16;
    constexpr int SEGS = NOC / 16;
    constexpr int LP   = NOC + 8;
    constexpr int CP   = CPG * 8;
    constexpr int SMEM = (SLAB * 2 > 64 * LP * 2) ? SLAB * 2 : 64 * LP * 2;
    __shared__ __align__(16) char smem[SMEM];
    __shared__ int s_kt[KSTEPS * 4];
    unsigned short* slab = reinterpret_cast<unsigned short*>(smem);
    unsigned short* s_c  = reinterpret_cast<unsigned short*>(smem);

    const int tid  = threadIdx.x;
    const int mb   = blockIdx.x;
    const int ocb  = blockIdx.y;
    const int nl   = blockIdx.z;
    const int lane = tid & 63;
    const int wv   = tid >> 6;
    const int frow = lane & 15;
    const int fq   = lane >> 4;

    if (tid < KSTEPS * 4) s_kt[tid] = ktab[tid];

    const int p0    = mb * Mblk;
    const int y0    = p0 / W;
    const int plast = (p0 + Mblk < Mtot ? p0 + Mblk : Mtot) - 1;
    const int rows  = plast / W - y0 + KH;

    const unsigned short* in_n =
        inP + (size_t)nl * inSS + (size_t)y0 * Wp * CP;
    const int nchunks = rows * Wp * CPG;
    for (int q = tid; q < nchunks; q += 256) {
        int pix = q / CPG, c8 = q - pix * CPG;
        uint4 v = reinterpret_cast<const uint4*>(in_n)[q];
        *reinterpret_cast<uint4*>(&slab[pix * CL + c8 * 8]) = v;
    }

    int ldsb[MFRAG];
    #pragma unroll
    for (int mf = 0; mf < MFRAG; ++mf) {
        int p  = p0 + mf * 64 + wv * 16 + frow;
        int pc = p < Mtot ? p : (Mtot - 1);
        int y  = pc / W;
        int x  = pc - y * W;
        ldsb[mf] = ((y - y0) * Wp + x) * CL;
    }
    const unsigned short* wbase =
        wPT + ((size_t)(ocb * NOC + frow)) * 32 + fq * 8;

    f32x4 acc[MFRAG][NG];
    #pragma unroll
    for (int mf = 0; mf < MFRAG; ++mf)
        #pragma unroll
        for (int ng = 0; ng < NG; ++ng)
            acc[mf][ng] = (f32x4){0.f, 0.f, 0.f, 0.f};

    __syncthreads();

    for (int kb = 0; kb < KSTEPS; ++kb) {
        int go = s_kt[kb * 4 + fq];
        bf16x8 af[MFRAG];
        #pragma unroll
        for (int mf = 0; mf < MFRAG; ++mf)
            af[mf] = *reinterpret_cast<const bf16x8*>(&slab[ldsb[mf] + go]);
        const unsigned short* wk = wbase + (size_t)kb * COUT * 32;
        #pragma unroll
        for (int ng = 0; ng < NG; ++ng) {
            bf16x8 bf = *reinterpret_cast<const bf16x8*>(wk + ng * 16 * 32);
            #pragma unroll
            for (int mf = 0; mf < MFRAG; ++mf)
                acc[mf][ng] = __builtin_amdgcn_mfma_f32_16x16x32_bf16(
                    af[mf], bf, acc[mf][ng], 0, 0, 0);
        }
    }

    unsigned short* out_n = out + (size_t)nl * outSS;
    #pragma unroll
    for (int mf = 0; mf < MFRAG; ++mf) {
        __syncthreads();
        #pragma unroll
        for (int ng = 0; ng < NG; ++ng) {
            float bv = bias[ocb * NOC + ng * 16 + frow];
            #pragma unroll
            for (int j = 0; j < 4; ++j)
                s_c[(wv * 16 + fq * 4 + j) * LP + ng * 16 + frow] =
                    f2bf(fmaxf(acc[mf][ng][j] + bv, 0.0f));
        }
        __syncthreads();
        for (int t = tid; t < 64 * SEGS; t += 256) {
            int row = t / SEGS, seg = t % SEGS;
            int p = p0 + mf * 64 + row;
            if (p < Mtot) {
                ushort8 v0 = *reinterpret_cast<const ushort8*>(
                    &s_c[row * LP + seg * 16]);
                ushort8 v1 = *reinterpret_cast<const ushort8*>(
                    &s_c[row * LP + seg * 16 + 8]);
                unsigned short* op =
                    out_n + (size_t)p * COUT + ocb * NOC + seg * 16;
                *reinterpret_cast<ushort8*>(op) = v0;
                *reinterpret_cast<ushort8*>(op + 8) = v1;
            }
        }
    }
}

// ---------------------------------------------------------------------------
// 5) MaxPool 3x3 s2 VALID, HWC, ushort8 (post-ReLU: u16 max).
// ---------------------------------------------------------------------------
__global__ __launch_bounds__(256) void pool_k(
    const unsigned short* __restrict__ in, unsigned short* __restrict__ out,
    int CG, int C, int W, int inSS,
    int HO, int WO, int Wpo, int outSS, int total)
{
    int idx = blockIdx.x * 256 + threadIdx.x;
    if (idx >= total) return;
    int cg = idx % CG;
    int t  = idx / CG;
    int x  = t % WO;
    t /= WO;
    int y  = t % HO;
    int nl = t / HO;

    const unsigned short* pin = in + (size_t)nl * inSS + cg * 8;
    ushort8 mx = {0,0,0,0,0,0,0,0};
    #pragma unroll
    for (int dy = 0; dy < 3; ++dy)
        #pragma unroll
        for (int dx = 0; dx < 3; ++dx) {
            ushort8 v = *reinterpret_cast<const ushort8*>(
                pin + ((size_t)(2 * y + dy) * W + (2 * x + dx)) * C);
            #pragma unroll
            for (int j = 0; j < 8; ++j) mx[j] = v[j] > mx[j] ? v[j] : mx[j];
        }
    *reinterpret_cast<ushort8*>(
        out + (size_t)nl * outSS +
        ((size_t)(y + 1) * Wpo + (x + 1)) * C + cg * 8) = mx;
}

// ---------------------------------------------------------------------------
// 6) Fused pool2 (3x3 s2 on [17][17][256]) + global average pool -> fp32
// ---------------------------------------------------------------------------
__global__ __launch_bounds__(512) void pool2gap_k(
    const unsigned short* __restrict__ in, float* __restrict__ out,
    int inSS, int n0)
{
    __shared__ float part[256];
    const int nl = blockIdx.x;
    const int c    = threadIdx.x & 255;
    const int half = threadIdx.x >> 8;
    const unsigned short* p = in + (size_t)nl * inSS + c;
    float s = 0.0f;
    for (int w = half * 32; w < half * 32 + 32; ++w) {
        int y = w >> 3, x = w & 7;
        unsigned short mx = 0;
        #pragma unroll
        for (int dy = 0; dy < 3; ++dy)
            #pragma unroll
            for (int dx = 0; dx < 3; ++dx) {
                unsigned short v = p[((size_t)(2*y+dy) * 17 + (2*x+dx)) * 256];
                mx = v > mx ? v : mx;
            }
        s += bf2f(mx);
    }
    if (half) part[c] = s;
    __syncthreads();
    if (!half) out[(size_t)(n0 + nl) * 256 + c] = (s + part[c]) * (1.0f / 64.0f);
}

// ---------------------------------------------------------------------------
// 7) Fused 3-layer FC head (256->512->256->512), one block per sample
// ---------------------------------------------------------------------------
__global__ __launch_bounds__(256) void fc_fused_k(
    const float* __restrict__ in,
    const float* __restrict__ w0T, const float* __restrict__ b0,
    const float* __restrict__ w1T, const float* __restrict__ b1,
    const float* __restrict__ w2T, const float* __restrict__ b2,
    float* __restrict__ out)
{
    __shared__ float s_in[256], s_h0[512], s_h1[256];
    const int n = blockIdx.x, t = threadIdx.x;
    s_in[t] = in[(size_t)n * 256 + t];
    __syncthreads();
    float a0 = 0.f, a1 = 0.f;
    for (int i = 0; i < 256; ++i) {
        float v = s_in[i];
        a0 += v * w0T[i * 512 + t];
        a1 += v * w0T[i * 512 + t + 256];
    }
    s_h0[t]       = fmaxf(a0 + b0[t], 0.0f);
    s_h0[t + 256] = fmaxf(a1 + b0[t + 256], 0.0f);
    __syncthreads();
    float h = 0.f;
    for (int i = 0; i < 512; ++i) h += s_h0[i] * w1T[i * 256 + t];
    s_h1[t] = fmaxf(h + b1[t], 0.0f);
    __syncthreads();
    a0 = 0.f; a1 = 0.f;
    for (int i = 0; i < 256; ++i) {
        float v = s_h1[i];
        a0 += v * w2T[i * 512 + t];
        a1 += v * w2T[i * 512 + t + 256];
    }
    out[(size_t)n * 512 + t]       = a0 + b2[t];
    out[(size_t)n * 512 + t + 256] = a1 + b2[t + 256];
}

// ---------------------------------------------------------------------------
// Launch. 10 kernels/call.
// ---------------------------------------------------------------------------
extern "C" void kernel_launch(void* const* d_in, const int* in_sizes, int n_in,
                              void* d_out, int out_size, void* d_ws, size_t ws_size,
                              hipStream_t stream)
{
    const int*   X   = (const int*)d_in[0];
    const int*   rm  = (const int*)d_in[1];
    const float* emb = (const float*)d_in[2];
    const float* cw0 = (const float*)d_in[3];
    const float* cb0 = (const float*)d_in[4];
    const float* cw1 = (const float*)d_in[5];
    const float* cb1 = (const float*)d_in[6];
    const float* cw2 = (const float*)d_in[7];
    const float* cb2 = (const float*)d_in[8];
    const float* fw0 = (const float*)d_in[9];
    const float* fb0 = (const float*)d_in[10];
    const float* fw1 = (const float*)d_in[11];
    const float* fb1 = (const float*)d_in[12];
    const float* fw2 = (const float*)d_in[13];
    const float* fb2 = (const float*)d_in[14];
    float* out = (float*)d_out;

    char* p = (char*)d_ws;
    auto alloc = [&](size_t bytes) -> char* {
        char* r = p; p += (bytes + 255) & ~(size_t)255; return r;
    };
    unsigned short* WP0 = (unsigned short*)alloc((size_t)32 * 64 * 32 * 2);
    unsigned short* WP1 = (unsigned short*)alloc((size_t)18 * 128 * 32 * 2);
    unsigned short* WP2 = (unsigned short*)alloc((size_t)36 * 256 * 32 * 2);
    int* KT0 = (int*)alloc(128 * 4);
    int* KT1 = (int*)alloc(72 * 4);
    int* KT2 = (int*)alloc(144 * 4);
    unsigned long long* MASKS = (unsigned long long*)alloc(RR * 8);
    float* W0T  = (float*)alloc((size_t)256 * 512 * 4);
    float* W1T  = (float*)alloc((size_t)512 * 256 * 4);
    float* W2T  = (float*)alloc((size_t)256 * 512 * 4);
    float* GAPB = (float*)alloc((size_t)NB * 256 * 4);
    size_t fixed_bytes = (size_t)(p - (char*)d_ws);

    const size_t A_FL = 231040, B_FL = 331776, C_FL = 133824;   // u16
    const size_t per_sample = (A_FL + B_FL + C_FL) * 2 + 768;
    int Bc = 128;
    while (Bc > 1 && fixed_bytes + (size_t)Bc * per_sample > ws_size) Bc >>= 1;

    unsigned short* bufA = (unsigned short*)alloc((size_t)Bc * A_FL * 2);
    unsigned short* bufC = (unsigned short*)alloc((size_t)Bc * C_FL * 2);
    unsigned short* bufB = (unsigned short*)alloc((size_t)Bc * B_FL * 2);

    // ---- consolidated prep (1 launch) ----
    prep_k<<<3235, 256, 0, stream>>>(
        rm, MASKS, cw0, WP0, cw1, WP1, cw2, WP2,
        KT0, KT1, KT2, fw0, W0T, fw1, W1T, fw2, W2T);

    // ---- chunked pipeline ----
    for (int n0 = 0; n0 < NB; n0 += Bc) {
        int nb1 = (Bc * 592 * 5 + 255) / 256;
        int nbc1 = (Bc * 144 * 8 + 255) / 256;
        int nbc2 = (Bc * 72 * 16 + 255) / 256;
        border3_k<<<nb1 + nbc1 + nbc2, 256, 0, stream>>>(
            bufA, bufC, (int)A_FL, (int)C_FL, nb1, nb1 + nbc1, Bc);

        // encode -> A (HWC G [76][76][40], interior +2)
        encode_k<<<dim3(Bc, 18), 512, 0, stream>>>(X, MASKS, emb, bufA, n0, (int)A_FL);

        // conv0: A -> B  (15 24x16 tiles/sample, COUT=64, 32 ksteps)
        conv0_tile_k<32><<<dim3(15, Bc), 256, 0, stream>>>(
            bufA, WP0, KT0, cb0, bufB, (int)A_FL, (int)B_FL);
        // pool0: B [72][72][64] -> C P0p [37][37][64] interior +1
        pool_k<<<(Bc * 35 * 35 * 8 + 255) / 256, 256, 0, stream>>>(
            bufB, bufC, 8, 64, 72, (int)B_FL,
            35, 35, 37, (int)C_FL, Bc * 35 * 35 * 8);

        // conv1: C -> A  (M=1225, Mblk=256 -> 5 mblocks, COUT=128)
        conv_mfma_k<4, 8, 3, 8, 72, 29304, 18><<<dim3(5, 1, Bc), 256, 0, stream>>>(
            bufC, WP1, KT1, cb1, bufA, 35, 37,
            1225, (int)C_FL, (int)A_FL, 128);
        // pool1: A [35][35][128] -> C+87616 P1p [19][19][128] interior +1
        pool_k<<<(Bc * 17 * 17 * 16 + 255) / 256, 256, 0, stream>>>(
            bufA, bufC + 87616, 16, 128, 35, (int)A_FL,
            17, 17, 19, (int)C_FL, Bc * 17 * 17 * 16);

        // conv2: C+87616 -> B  (M=289, Mblk=128 -> 3 mblocks, 2 oc-blocks)
        conv_mfma_k<2, 8, 3, 16, 136, 28424, 36><<<dim3(3, 2, Bc), 256, 0, stream>>>(
            bufC + 87616, WP2, KT2, cb2, bufB, 17, 19,
            289, (int)C_FL, (int)B_FL, 256);

        // fused pool2 + GAP: B [17][17][256] -> GAPB fp32
        pool2gap_k<<<Bc, 512, 0, stream>>>(bufB, GAPB, (int)B_FL, n0);
    }

    // fused FC head
    fc_fused_k<<<NB, 256, 0, stream>>>(GAPB, W0T, fb0, W1T, fb1, W2T, fb2, out);
}

// Round 17
// 497.631 us; speedup vs baseline: 1.0432x; 1.0048x over previous
//
#include <hip/hip_runtime.h>
#include <hip/hip_bf16.h>
#include <cstdint>
#include <cstddef>

#define NB      128
#define RR      300
#define EMB     32

typedef __bf16 bf16x8 __attribute__((ext_vector_type(8)));
typedef float  f32x4  __attribute__((ext_vector_type(4)));
typedef unsigned short ushort8 __attribute__((ext_vector_type(8)));

__device__ __forceinline__ unsigned short f2bf(float f) {
    union { __hip_bfloat16 h; unsigned short u; } c;
    c.h = __float2bfloat16(f);
    return c.u;
}
__device__ __forceinline__ float bf2f(unsigned short u) {
    union { __hip_bfloat16 h; unsigned short u; } c;
    c.u = u;
    return __bfloat162float(c.h);
}

// ---------------------------------------------------------------------------
// helpers for the consolidated prep kernel
// ---------------------------------------------------------------------------
__device__ __forceinline__ void wpack_body(
    const float* __restrict__ w, unsigned short* __restrict__ wPT,
    int COUT, int CIN, int KK, int gpc, int idx, int total)
{
    if (idx >= total) return;
    int kk = idx & 31;
    int t  = idx >> 5;
    int oc = t % COUT;
    int kb = t / COUT;
    int g  = kb * 4 + (kk >> 3);
    int j  = kk & 7;
    int shift = g / gpc;
    int ci    = (g % gpc) * 8 + j;
    float v = (shift < KK && ci < CIN)
        ? w[(size_t)oc * CIN * KK + (size_t)ci * KK + shift] : 0.0f;
    wPT[idx] = f2bf(v);
}

__device__ __forceinline__ void fcT_body(
    const float* __restrict__ w, float* __restrict__ wT, int O, int I, int idx)
{
    if (idx >= O * I) return;
    int i = idx % I, o = idx / I;
    wT[(size_t)i * O + o] = w[idx];
}

// ---------------------------------------------------------------------------
// 1) Consolidated prep: masks + wpack x3 + ktab x3 + fcT x3 in ONE launch.
// ---------------------------------------------------------------------------
__global__ __launch_bounds__(256) void prep_k(
    const int* __restrict__ rm, unsigned long long* __restrict__ masks,
    const float* __restrict__ cw0, unsigned short* __restrict__ WP0,
    const float* __restrict__ cw1, unsigned short* __restrict__ WP1,
    const float* __restrict__ cw2, unsigned short* __restrict__ WP2,
    int* __restrict__ kt0, int* __restrict__ kt1, int* __restrict__ kt2,
    const float* __restrict__ fw0, float* __restrict__ W0T,
    const float* __restrict__ fw1, float* __restrict__ W1T,
    const float* __restrict__ fw2, float* __restrict__ W2T)
{
    const int b = blockIdx.x;
    const int t = threadIdx.x;
    if (b < 2) {
        int r = b * 256 + t;
        if (r < RR) {
            unsigned long long m = 0ull;
            #pragma unroll
            for (int k = 0; k < 64; ++k)
                if (rm[r * 64 + k]) m |= (1ull << k);
            masks[r] = m;
        }
    } else if (b < 258) {
        wpack_body(cw0, WP0, 64, 33, 25, 5, (b - 2) * 256 + t, 32 * 64 * 32);
    } else if (b < 546) {
        wpack_body(cw1, WP1, 128, 64, 9, 8, (b - 258) * 256 + t, 18 * 128 * 32);
    } else if (b < 1698) {
        wpack_body(cw2, WP2, 256, 128, 9, 16, (b - 546) * 256 + t, 36 * 256 * 32);
    } else if (b < 1699) {
        #pragma unroll
        for (int which = 0; which < 3; ++which) {
            int ngr, gpc, K, Wp, CL;
            int* dst;
            if (which == 0)      { ngr = 128; gpc = 5;  K = 5; Wp = 20; CL = 40;  dst = kt0; }
            else if (which == 1) { ngr = 72;  gpc = 8;  K = 3; Wp = 37; CL = 72;  dst = kt1; }
            else                 { ngr = 144; gpc = 16; K = 3; Wp = 19; CL = 136; dst = kt2; }
            if (t < ngr) {
                int shift = t / gpc;
                int off = 0;
                if (shift < K * K) {
                    int ky = shift / K, kx = shift % K;
                    off = (ky * Wp + kx) * CL + (t % gpc) * 8;
                }
                dst[t] = off;
            }
        }
    } else if (b < 2211) {
        fcT_body(fw0, W0T, 512, 256, (b - 1699) * 256 + t);
    } else if (b < 2723) {
        fcT_body(fw1, W1T, 256, 512, (b - 2211) * 256 + t);
    } else {
        fcT_body(fw2, W2T, 512, 256, (b - 2723) * 256 + t);
    }
}

// ---------------------------------------------------------------------------
// 2) Border zero for the two bufC padded buffers (bufA halo handled by
//    encode_k now).
// ---------------------------------------------------------------------------
__device__ __forceinline__ void border_body(
    unsigned short* __restrict__ base, int Hp, int Wp, int CPG, int pad,
    int sampleStride, int nborder, int idx, int total)
{
    if (idx >= total) return;
    int c8 = idx % CPG;
    int t  = idx / CPG;
    int bi = t % nborder;
    int nl = t / nborder;

    int topN = pad * Wp;
    int y, x;
    if (bi < topN) {
        y = bi / Wp; x = bi - y * Wp;
    } else if (bi < 2 * topN) {
        int b2 = bi - topN;
        y = Hp - pad + b2 / Wp; x = b2 % Wp;
    } else {
        int mid = bi - 2 * topN;
        int rowlen = 2 * pad;
        y = pad + mid / rowlen;
        int r = mid % rowlen;
        x = r < pad ? r : Wp - pad + (r - pad);
    }
    uint4 z = make_uint4(0, 0, 0, 0);
    *reinterpret_cast<uint4*>(
        &base[((size_t)nl * sampleStride) +
              ((size_t)y * Wp + x) * (CPG * 8) + c8 * 8]) = z;
}

__global__ __launch_bounds__(256) void border2_k(
    unsigned short* __restrict__ bufC, int C_SS, int nb1, int Bc)
{
    int b = blockIdx.x;
    int t = threadIdx.x;
    if (b < nb1) {
        border_body(bufC, 37, 37, 8, 1, C_SS, 144, b * 256 + t, Bc * 144 * 8);
    } else {
        border_body(bufC + 87616, 19, 19, 16, 1, C_SS, 72,
                    (b - nb1) * 256 + t, Bc * 72 * 16);
    }
}

// ---------------------------------------------------------------------------
// 3) Encode, banded HWC. v5 + halo: also zeroes bufA's halo (band 0/17
//    write top/bottom rows; every band writes its rows' L/R halo cols).
// ---------------------------------------------------------------------------
__global__ __launch_bounds__(512) void encode_k(
    const int* __restrict__ X, const unsigned long long* __restrict__ masks,
    const float* __restrict__ emb, unsigned short* __restrict__ G,
    int n0, int sampleStride)
{
    __shared__ float tile[4][72][33];
    __shared__ unsigned s_pos[RR];
    __shared__ unsigned long long s_mask[RR];
    __shared__ unsigned short s_list[320];
    __shared__ float s_emb[64 * 33];
    __shared__ int s_woff[8];
    __shared__ int s_cnt;

    const int nl = blockIdx.x, band = blockIdx.y;
    const int by = band * 4;
    const int n  = n0 + nl;
    const int tid = threadIdx.x;

    float* tf = &tile[0][0][0];
    for (int i = tid; i < 4 * 72 * 33; i += 512) tf[i] = 0.0f;

    const int2* Xp = reinterpret_cast<const int2*>(X);
    bool hot = false;
    if (tid < RR) {
        int2 pos = Xp[n * RR + tid];
        s_pos[tid]  = (unsigned)pos.x | ((unsigned)pos.y << 16);
        s_mask[tid] = masks[tid];
        hot = (pos.y <= by + 3) && (pos.y + 7 >= by);
    }
    unsigned long long bal = __ballot(hot);
    if ((tid & 63) == 0) s_woff[tid >> 6] = (int)__popcll(bal);
    __syncthreads();
    if (tid == 0) {
        int acc = 0;
        #pragma unroll
        for (int w = 0; w < 8; ++w) { int c = s_woff[w]; s_woff[w] = acc; acc += c; }
        s_cnt = acc;
    }
    __syncthreads();
    if (hot) {
        int w = tid >> 6, b = tid & 63;
        unsigned long long before = (b == 0) ? 0ull : (bal & ((1ull << b) - 1ull));
        s_list[s_woff[w] + (int)__popcll(before)] = (unsigned short)tid;
    }
    __syncthreads();

    const int lane = tid & 63;
    const int wvi  = tid >> 6;          // 0..7
    const int dx   = lane >> 3;         // 0..7
    const int c0   = (lane & 7) * 5;    // channels [c0, c0+5) ∩ [0,33)
    const int cnt  = s_cnt;

    for (int base = 0; base < cnt; base += 64) {
        int cn = cnt - base; if (cn > 64) cn = 64;
        for (int i = tid; i < cn * 33; i += 512) {
            int hi = i / 33, cc = i - hi * 33;
            int r = s_list[base + hi];
            s_emb[i] = (cc == 0) ? 1.0f : emb[r * EMB + cc - 1];
        }
        __syncthreads();

        int j = wvi;
        for (; j + 8 < cn; j += 16) {
            int rA = s_list[base + j];
            int rB = s_list[base + j + 8];
            unsigned pA = s_pos[rA], pB = s_pos[rB];
            unsigned long long mA = s_mask[rA] >> (dx * 8);
            unsigned long long mB = s_mask[rB] >> (dx * 8);
            int xA = (pA & 0xffff) + dx, yA = pA >> 16;
            int xB = (pB & 0xffff) + dx, yB = pB >> 16;
            float eA[5], eB[5];
            #pragma unroll
            for (int q = 0; q < 5; ++q) {
                eA[q] = (c0 + q < 33) ? s_emb[j * 33 + c0 + q] : 0.0f;
                eB[q] = (c0 + q < 33) ? s_emb[(j + 8) * 33 + c0 + q] : 0.0f;
            }
            #pragma unroll
            for (int dyb = 0; dyb < 4; ++dyb) {
                int dA = by + dyb - yA;
                if ((unsigned)dA < 8u && ((mA >> dA) & 1ull)) {
                    #pragma unroll
                    for (int q = 0; q < 5; ++q)
                        if (c0 + q < 33)
                            atomicAdd(&tile[dyb][xA][c0 + q], eA[q]);
                }
                int dB = by + dyb - yB;
                if ((unsigned)dB < 8u && ((mB >> dB) & 1ull)) {
                    #pragma unroll
                    for (int q = 0; q < 5; ++q)
                        if (c0 + q < 33)
                            atomicAdd(&tile[dyb][xB][c0 + q], eB[q]);
                }
            }
        }
        for (; j < cn; j += 8) {
            int r = s_list[base + j];
            unsigned pxy = s_pos[r];
            int px = pxy & 0xffff, py = pxy >> 16;
            unsigned long long mm = s_mask[r] >> (dx * 8);
            int x = px + dx;
            float ev[5];
            #pragma unroll
            for (int q = 0; q < 5; ++q)
                ev[q] = (c0 + q < 33) ? s_emb[j * 33 + c0 + q] : 0.0f;
            #pragma unroll
            for (int dyb = 0; dyb < 4; ++dyb) {
                int dyr = by + dyb - py;
                if ((unsigned)dyr < 8u && ((mm >> dyr) & 1ull)) {
                    #pragma unroll
                    for (int q = 0; q < 5; ++q)
                        if (c0 + q < 33)
                            atomicAdd(&tile[dyb][x][c0 + q], ev[q]);
                }
            }
        }
        __syncthreads();
    }
    __syncthreads();

    // write-out: 4 rows x 72 px x 40ch as uint2 (4ch) chunks
    unsigned short* Gn = G + (size_t)nl * sampleStride;
    for (int i = tid; i < 4 * 72 * 10; i += 512) {
        int cc = i % 10;
        int t  = i / 10;
        int x  = t % 72;
        int dyb = t / 72;
        int c0w = cc * 4;
        unsigned short r[4];
        #pragma unroll
        for (int j = 0; j < 4; ++j)
            r[j] = (c0w + j < 33) ? f2bf(tile[dyb][x][c0w + j]) : 0;
        uint2 pk;
        pk.x = (unsigned)r[0] | ((unsigned)r[1] << 16);
        pk.y = (unsigned)r[2] | ((unsigned)r[3] << 16);
        *reinterpret_cast<uint2*>(
            &Gn[((size_t)(by + dyb + 2) * 76 + (x + 2)) * 40 + c0w]) = pk;
    }

    // halo: left/right cols (0,1,74,75) for this band's 4 rows
    uint2 zz; zz.x = 0; zz.y = 0;
    for (int i = tid; i < 160; i += 512) {
        int cc = i % 10;
        int t  = i / 10;
        int ci = t & 3;
        int dyb = t >> 2;
        int x = ci < 2 ? ci : 72 + ci;     // 0,1,74,75
        *reinterpret_cast<uint2*>(
            &Gn[((size_t)(by + dyb + 2) * 76 + x) * 40 + cc * 4]) = zz;
    }
    // halo: top rows 0-1 (band 0) / bottom rows 74-75 (band 17)
    if (band == 0 || band == 17) {
        int rbase = band == 0 ? 0 : 74;
        for (int i = tid; i < 2 * 76 * 10; i += 512) {
            int cc = i % 10;
            int t  = i / 10;
            int x  = t % 76;
            int r  = t / 76;
            *reinterpret_cast<uint2*>(
                &Gn[((size_t)(rbase + r) * 76 + x) * 40 + cc * 4]) = zz;
        }
    }
}

// ---------------------------------------------------------------------------
// 4a) conv0: 24x16-spatial-tile implicit-GEMM, bf16 MFMA 16x16x32.
//     Round-14 body (proven fastest: ~104 µs). No B-prefetch (r16 showed
//     it regresses), __launch_bounds__(256,3), ktab in LDS.
// ---------------------------------------------------------------------------
template<int KSTEPS>
__global__ __launch_bounds__(256, 3) void conv0_tile_k(
    const unsigned short* __restrict__ inP,   // [B][76][76][40] bf16
    const unsigned short* __restrict__ wPT,   // [KSTEPS][64][32] bf16
    const int* __restrict__ ktab,             // [KSTEPS*4] LDS offsets
    const float* __restrict__ bias,
    unsigned short* __restrict__ out,         // [B][5184][64] bf16
    int inSS, int outSS)
{
    constexpr int CL = 40;
    constexpr int LP = 72;
    __shared__ __align__(16) unsigned short slab[28 * 20 * CL];  // 44800 B
    __shared__ int s_kt[KSTEPS * 4];
    unsigned short* s_c = slab;

    const int tid = threadIdx.x;
    const int tl  = blockIdx.x;           // 0..14
    const int nl  = blockIdx.y;
    const int tyi = tl / 5, txi = tl % 5;
    const int y0 = tyi * 24;
    const int x0 = txi < 4 ? txi * 16 : 56;

    const int lane = tid & 63, wv = tid >> 6, frow = lane & 15, fq = lane >> 4;

    if (tid < KSTEPS * 4) s_kt[tid] = ktab[tid];

    const unsigned short* in_n = inP + (size_t)nl * inSS;
    {
        const uint4* src = reinterpret_cast<const uint4*>(in_n);
        uint4* dst = reinterpret_cast<uint4*>(slab);
        #pragma unroll
        for (int it = 0; it < 11; ++it) {
            int q = tid + it * 256;
            if (q < 2800) {
                int r = q / 100, c = q - r * 100;
                dst[q] = src[((y0 + r) * 76 + x0) * 5 + c];
            }
        }
    }

    int ldsb[6];
    #pragma unroll
    for (int mf = 0; mf < 6; ++mf)
        ldsb[mf] = ((mf * 4 + wv) * 20 + frow) * CL;

    const unsigned short* wbase = wPT + (size_t)frow * 32 + fq * 8;

    f32x4 acc[6][4];
    #pragma unroll
    for (int a = 0; a < 6; ++a)
        #pragma unroll
        for (int b = 0; b < 4; ++b) acc[a][b] = (f32x4){0.f, 0.f, 0.f, 0.f};

    __syncthreads();

    #pragma unroll 2
    for (int kb = 0; kb < KSTEPS; ++kb) {
        int go = s_kt[kb * 4 + fq];
        bf16x8 af[6];
        #pragma unroll
        for (int mf = 0; mf < 6; ++mf)
            af[mf] = *reinterpret_cast<const bf16x8*>(&slab[ldsb[mf] + go]);
        const unsigned short* wk = wbase + (size_t)kb * 64 * 32;
        #pragma unroll
        for (int ng = 0; ng < 4; ++ng) {
            bf16x8 bf = *reinterpret_cast<const bf16x8*>(wk + ng * 16 * 32);
            #pragma unroll
            for (int mf = 0; mf < 6; ++mf)
                acc[mf][ng] = __builtin_amdgcn_mfma_f32_16x16x32_bf16(
                    af[mf], bf, acc[mf][ng], 0, 0, 0);
        }
    }

    unsigned short* out_n = out + (size_t)nl * outSS;
    const int erow = tid >> 2, eseg = tid & 3;
    #pragma unroll
    for (int mf = 0; mf < 6; ++mf) {
        __syncthreads();
        #pragma unroll
        for (int ng = 0; ng < 4; ++ng) {
            float bv = bias[ng * 16 + frow];
            #pragma unroll
            for (int j = 0; j < 4; ++j)
                s_c[(wv * 16 + fq * 4 + j) * LP + ng * 16 + frow] =
                    f2bf(fmaxf(acc[mf][ng][j] + bv, 0.0f));
        }
        __syncthreads();
        {
            int ty = mf * 4 + (erow >> 4);
            int tx = erow & 15;
            int pos = (y0 + ty) * 72 + (x0 + tx);
            ushort8 v0 = *reinterpret_cast<const ushort8*>(
                &s_c[erow * LP + eseg * 16]);
            ushort8 v1 = *reinterpret_cast<const ushort8*>(
                &s_c[erow * LP + eseg * 16 + 8]);
            unsigned short* op = out_n + (size_t)pos * 64 + eseg * 16;
            *reinterpret_cast<ushort8*>(op) = v0;
            *reinterpret_cast<ushort8*>(op + 8) = v1;
        }
    }
}

// ---------------------------------------------------------------------------
// 4b) Generic row-slab implicit-GEMM conv (conv1/conv2), bf16 MFMA 16x16x32.
// ---------------------------------------------------------------------------
template<int MFRAG, int NG, int KH, int CPG, int CL, int SLAB, int KSTEPS>
__global__ __launch_bounds__(256, 2) void conv_mfma_k(
    const unsigned short* __restrict__ inP,
    const unsigned short* __restrict__ wPT,
    const int* __restrict__ ktab,
    const float* __restrict__ bias,
    unsigned short* __restrict__ out,
    int W, int Wp, int Mtot, int inSS, int outSS, int COUT)
{
    constexpr int Mblk = MFRAG * 64;
    constexpr int NOC  = NG * 16;
    constexpr int SEGS = NOC / 16;
    constexpr int LP   = NOC + 8;
    constexpr int CP   = CPG * 8;
    constexpr int SMEM = (SLAB * 2 > 64 * LP * 2) ? SLAB * 2 : 64 * LP * 2;
    __shared__ __align__(16) char smem[SMEM];
    __shared__ int s_kt[KSTEPS * 4];
    unsigned short* slab = reinterpret_cast<unsigned short*>(smem);
    unsigned short* s_c  = reinterpret_cast<unsigned short*>(smem);

    const int tid  = threadIdx.x;
    const int mb   = blockIdx.x;
    const int ocb  = blockIdx.y;
    const int nl   = blockIdx.z;
    const int lane = tid & 63;
    const int wv   = tid >> 6;
    const int frow = lane & 15;
    const int fq   = lane >> 4;

    if (tid < KSTEPS * 4) s_kt[tid] = ktab[tid];

    const int p0    = mb * Mblk;
    const int y0    = p0 / W;
    const int plast = (p0 + Mblk < Mtot ? p0 + Mblk : Mtot) - 1;
    const int rows  = plast / W - y0 + KH;

    const unsigned short* in_n =
        inP + (size_t)nl * inSS + (size_t)y0 * Wp * CP;
    const int nchunks = rows * Wp * CPG;
    for (int q = tid; q < nchunks; q += 256) {
        int pix = q / CPG, c8 = q - pix * CPG;
        uint4 v = reinterpret_cast<const uint4*>(in_n)[q];
        *reinterpret_cast<uint4*>(&slab[pix * CL + c8 * 8]) = v;
    }

    int ldsb[MFRAG];
    #pragma unroll
    for (int mf = 0; mf < MFRAG; ++mf) {
        int p  = p0 + mf * 64 + wv * 16 + frow;
        int pc = p < Mtot ? p : (Mtot - 1);
        int y  = pc / W;
        int x  = pc - y * W;
        ldsb[mf] = ((y - y0) * Wp + x) * CL;
    }
    const unsigned short* wbase =
        wPT + ((size_t)(ocb * NOC + frow)) * 32 + fq * 8;

    f32x4 acc[MFRAG][NG];
    #pragma unroll
    for (int mf = 0; mf < MFRAG; ++mf)
        #pragma unroll
        for (int ng = 0; ng < NG; ++ng)
            acc[mf][ng] = (f32x4){0.f, 0.f, 0.f, 0.f};

    __syncthreads();

    for (int kb = 0; kb < KSTEPS; ++kb) {
        int go = s_kt[kb * 4 + fq];
        bf16x8 af[MFRAG];
        #pragma unroll
        for (int mf = 0; mf < MFRAG; ++mf)
            af[mf] = *reinterpret_cast<const bf16x8*>(&slab[ldsb[mf] + go]);
        const unsigned short* wk = wbase + (size_t)kb * COUT * 32;
        #pragma unroll
        for (int ng = 0; ng < NG; ++ng) {
            bf16x8 bf = *reinterpret_cast<const bf16x8*>(wk + ng * 16 * 32);
            #pragma unroll
            for (int mf = 0; mf < MFRAG; ++mf)
                acc[mf][ng] = __builtin_amdgcn_mfma_f32_16x16x32_bf16(
                    af[mf], bf, acc[mf][ng], 0, 0, 0);
        }
    }

    unsigned short* out_n = out + (size_t)nl * outSS;
    #pragma unroll
    for (int mf = 0; mf < MFRAG; ++mf) {
        __syncthreads();
        #pragma unroll
        for (int ng = 0; ng < NG; ++ng) {
            float bv = bias[ocb * NOC + ng * 16 + frow];
            #pragma unroll
            for (int j = 0; j < 4; ++j)
                s_c[(wv * 16 + fq * 4 + j) * LP + ng * 16 + frow] =
                    f2bf(fmaxf(acc[mf][ng][j] + bv, 0.0f));
        }
        __syncthreads();
        for (int t = tid; t < 64 * SEGS; t += 256) {
            int row = t / SEGS, seg = t % SEGS;
            int p = p0 + mf * 64 + row;
            if (p < Mtot) {
                ushort8 v0 = *reinterpret_cast<const ushort8*>(
                    &s_c[row * LP + seg * 16]);
                ushort8 v1 = *reinterpret_cast<const ushort8*>(
                    &s_c[row * LP + seg * 16 + 8]);
                unsigned short* op =
                    out_n + (size_t)p * COUT + ocb * NOC + seg * 16;
                *reinterpret_cast<ushort8*>(op) = v0;
                *reinterpret_cast<ushort8*>(op + 8) = v1;
            }
        }
    }
}

// ---------------------------------------------------------------------------
// 5) MaxPool 3x3 s2 VALID, HWC, ushort8 (post-ReLU: u16 max).
// ---------------------------------------------------------------------------
__global__ __launch_bounds__(256) void pool_k(
    const unsigned short* __restrict__ in, unsigned short* __restrict__ out,
    int CG, int C, int W, int inSS,
    int HO, int WO, int Wpo, int outSS, int total)
{
    int idx = blockIdx.x * 256 + threadIdx.x;
    if (idx >= total) return;
    int cg = idx % CG;
    int t  = idx / CG;
    int x  = t % WO;
    t /= WO;
    int y  = t % HO;
    int nl = t / HO;

    const unsigned short* pin = in + (size_t)nl * inSS + cg * 8;
    ushort8 mx = {0,0,0,0,0,0,0,0};
    #pragma unroll
    for (int dy = 0; dy < 3; ++dy)
        #pragma unroll
        for (int dx = 0; dx < 3; ++dx) {
            ushort8 v = *reinterpret_cast<const ushort8*>(
                pin + ((size_t)(2 * y + dy) * W + (2 * x + dx)) * C);
            #pragma unroll
            for (int j = 0; j < 8; ++j) mx[j] = v[j] > mx[j] ? v[j] : mx[j];
        }
    *reinterpret_cast<ushort8*>(
        out + (size_t)nl * outSS +
        ((size_t)(y + 1) * Wpo + (x + 1)) * C + cg * 8) = mx;
}

// ---------------------------------------------------------------------------
// 6) Fused pool2 (3x3 s2 on [17][17][256]) + global average pool -> fp32
// ---------------------------------------------------------------------------
__global__ __launch_bounds__(512) void pool2gap_k(
    const unsigned short* __restrict__ in, float* __restrict__ out,
    int inSS, int n0)
{
    __shared__ float part[256];
    const int nl = blockIdx.x;
    const int c    = threadIdx.x & 255;
    const int half = threadIdx.x >> 8;
    const unsigned short* p = in + (size_t)nl * inSS + c;
    float s = 0.0f;
    for (int w = half * 32; w < half * 32 + 32; ++w) {
        int y = w >> 3, x = w & 7;
        unsigned short mx = 0;
        #pragma unroll
        for (int dy = 0; dy < 3; ++dy)
            #pragma unroll
            for (int dx = 0; dx < 3; ++dx) {
                unsigned short v = p[((size_t)(2*y+dy) * 17 + (2*x+dx)) * 256];
                mx = v > mx ? v : mx;
            }
        s += bf2f(mx);
    }
    if (half) part[c] = s;
    __syncthreads();
    if (!half) out[(size_t)(n0 + nl) * 256 + c] = (s + part[c]) * (1.0f / 64.0f);
}

// ---------------------------------------------------------------------------
// 7) Fused 3-layer FC head (256->512->256->512), one block per sample
// ---------------------------------------------------------------------------
__global__ __launch_bounds__(256) void fc_fused_k(
    const float* __restrict__ in,
    const float* __restrict__ w0T, const float* __restrict__ b0,
    const float* __restrict__ w1T, const float* __restrict__ b1,
    const float* __restrict__ w2T, const float* __restrict__ b2,
    float* __restrict__ out)
{
    __shared__ float s_in[256], s_h0[512], s_h1[256];
    const int n = blockIdx.x, t = threadIdx.x;
    s_in[t] = in[(size_t)n * 256 + t];
    __syncthreads();
    float a0 = 0.f, a1 = 0.f;
    for (int i = 0; i < 256; ++i) {
        float v = s_in[i];
        a0 += v * w0T[i * 512 + t];
        a1 += v * w0T[i * 512 + t + 256];
    }
    s_h0[t]       = fmaxf(a0 + b0[t], 0.0f);
    s_h0[t + 256] = fmaxf(a1 + b0[t + 256], 0.0f);
    __syncthreads();
    float h = 0.f;
    for (int i = 0; i < 512; ++i) h += s_h0[i] * w1T[i * 256 + t];
    s_h1[t] = fmaxf(h + b1[t], 0.0f);
    __syncthreads();
    a0 = 0.f; a1 = 0.f;
    for (int i = 0; i < 256; ++i) {
        float v = s_h1[i];
        a0 += v * w2T[i * 512 + t];
        a1 += v * w2T[i * 512 + t + 256];
    }
    out[(size_t)n * 512 + t]       = a0 + b2[t];
    out[(size_t)n * 512 + t + 256] = a1 + b2[t + 256];
}

// ---------------------------------------------------------------------------
// Launch. 10 kernels/call.
// ---------------------------------------------------------------------------
extern "C" void kernel_launch(void* const* d_in, const int* in_sizes, int n_in,
                              void* d_out, int out_size, void* d_ws, size_t ws_size,
                              hipStream_t stream)
{
    const int*   X   = (const int*)d_in[0];
    const int*   rm  = (const int*)d_in[1];
    const float* emb = (const float*)d_in[2];
    const float* cw0 = (const float*)d_in[3];
    const float* cb0 = (const float*)d_in[4];
    const float* cw1 = (const float*)d_in[5];
    const float* cb1 = (const float*)d_in[6];
    const float* cw2 = (const float*)d_in[7];
    const float* cb2 = (const float*)d_in[8];
    const float* fw0 = (const float*)d_in[9];
    const float* fb0 = (const float*)d_in[10];
    const float* fw1 = (const float*)d_in[11];
    const float* fb1 = (const float*)d_in[12];
    const float* fw2 = (const float*)d_in[13];
    const float* fb2 = (const float*)d_in[14];
    float* out = (float*)d_out;

    char* p = (char*)d_ws;
    auto alloc = [&](size_t bytes) -> char* {
        char* r = p; p += (bytes + 255) & ~(size_t)255; return r;
    };
    unsigned short* WP0 = (unsigned short*)alloc((size_t)32 * 64 * 32 * 2);
    unsigned short* WP1 = (unsigned short*)alloc((size_t)18 * 128 * 32 * 2);
    unsigned short* WP2 = (unsigned short*)alloc((size_t)36 * 256 * 32 * 2);
    int* KT0 = (int*)alloc(128 * 4);
    int* KT1 = (int*)alloc(72 * 4);
    int* KT2 = (int*)alloc(144 * 4);
    unsigned long long* MASKS = (unsigned long long*)alloc(RR * 8);
    float* W0T  = (float*)alloc((size_t)256 * 512 * 4);
    float* W1T  = (float*)alloc((size_t)512 * 256 * 4);
    float* W2T  = (float*)alloc((size_t)256 * 512 * 4);
    float* GAPB = (float*)alloc((size_t)NB * 256 * 4);
    size_t fixed_bytes = (size_t)(p - (char*)d_ws);

    const size_t A_FL = 231040, B_FL = 331776, C_FL = 133824;   // u16
    const size_t per_sample = (A_FL + B_FL + C_FL) * 2 + 768;
    int Bc = 128;
    while (Bc > 1 && fixed_bytes + (size_t)Bc * per_sample > ws_size) Bc >>= 1;

    unsigned short* bufA = (unsigned short*)alloc((size_t)Bc * A_FL * 2);
    unsigned short* bufC = (unsigned short*)alloc((size_t)Bc * C_FL * 2);
    unsigned short* bufB = (unsigned short*)alloc((size_t)Bc * B_FL * 2);

    // ---- consolidated prep (1 launch) ----
    prep_k<<<3235, 256, 0, stream>>>(
        rm, MASKS, cw0, WP0, cw1, WP1, cw2, WP2,
        KT0, KT1, KT2, fw0, W0T, fw1, W1T, fw2, W2T);

    // ---- chunked pipeline ----
    for (int n0 = 0; n0 < NB; n0 += Bc) {
        // border zero for the two bufC buffers (bufA halo done in encode)
        int nbc1 = (Bc * 144 * 8 + 255) / 256;
        int nbc2 = (Bc * 72 * 16 + 255) / 256;
        border2_k<<<nbc1 + nbc2, 256, 0, stream>>>(
            bufC, (int)C_FL, nbc1, Bc);

        // encode -> A (HWC G [76][76][40], interior +2, halo zeroed)
        encode_k<<<dim3(Bc, 18), 512, 0, stream>>>(X, MASKS, emb, bufA, n0, (int)A_FL);

        // conv0: A -> B  (15 24x16 tiles/sample, COUT=64, 32 ksteps)
        conv0_tile_k<32><<<dim3(15, Bc), 256, 0, stream>>>(
            bufA, WP0, KT0, cb0, bufB, (int)A_FL, (int)B_FL);
        // pool0: B [72][72][64] -> C P0p [37][37][64] interior +1
        pool_k<<<(Bc * 35 * 35 * 8 + 255) / 256, 256, 0, stream>>>(
            bufB, bufC, 8, 64, 72, (int)B_FL,
            35, 35, 37, (int)C_FL, Bc * 35 * 35 * 8);

        // conv1: C -> A  (M=1225, Mblk=256 -> 5 mblocks, COUT=128)
        conv_mfma_k<4, 8, 3, 8, 72, 29304, 18><<<dim3(5, 1, Bc), 256, 0, stream>>>(
            bufC, WP1, KT1, cb1, bufA, 35, 37,
            1225, (int)C_FL, (int)A_FL, 128);
        // pool1: A [35][35][128] -> C+87616 P1p [19][19][128] interior +1
        pool_k<<<(Bc * 17 * 17 * 16 + 255) / 256, 256, 0, stream>>>(
            bufA, bufC + 87616, 16, 128, 35, (int)A_FL,
            17, 17, 19, (int)C_FL, Bc * 17 * 17 * 16);

        // conv2: C+87616 -> B  (M=289, Mblk=128 -> 3 mblocks, 2 oc-blocks)
        conv_mfma_k<2, 8, 3, 16, 136, 28424, 36><<<dim3(3, 2, Bc), 256, 0, stream>>>(
            bufC + 87616, WP2, KT2, cb2, bufB, 17, 19,
            289, (int)C_FL, (int)B_FL, 256);

        // fused pool2 + GAP: B [17][17][256] -> GAPB fp32
        pool2gap_k<<<Bc, 512, 0, stream>>>(bufB, GAPB, (int)B_FL, n0);
    }

    // fused FC head
    fc_fused_k<<<NB, 256, 0, stream>>>(GAPB, W0T, fb0, W1T, fb1, W2T, fb2, out);
}

// Round 18
// 487.664 us; speedup vs baseline: 1.0645x; 1.0204x over previous
//
#include <hip/hip_runtime.h>
#include <hip/hip_bf16.h>
#include <cstdint>
#include <cstddef>

#define NB      128
#define RR      300
#define EMB     32

typedef __bf16 bf16x8 __attribute__((ext_vector_type(8)));
typedef float  f32x4  __attribute__((ext_vector_type(4)));
typedef unsigned short ushort8 __attribute__((ext_vector_type(8)));

__device__ __forceinline__ unsigned short f2bf(float f) {
    union { __hip_bfloat16 h; unsigned short u; } c;
    c.h = __float2bfloat16(f);
    return c.u;
}
__device__ __forceinline__ float bf2f(unsigned short u) {
    union { __hip_bfloat16 h; unsigned short u; } c;
    c.u = u;
    return __bfloat162float(c.h);
}

// ---------------------------------------------------------------------------
// helpers for the consolidated prep kernel
// ---------------------------------------------------------------------------
__device__ __forceinline__ void wpack_body(
    const float* __restrict__ w, unsigned short* __restrict__ wPT,
    int COUT, int CIN, int KK, int gpc, int idx, int total)
{
    if (idx >= total) return;
    int kk = idx & 31;
    int t  = idx >> 5;
    int oc = t % COUT;
    int kb = t / COUT;
    int g  = kb * 4 + (kk >> 3);
    int j  = kk & 7;
    int shift = g / gpc;
    int ci    = (g % gpc) * 8 + j;
    float v = (shift < KK && ci < CIN)
        ? w[(size_t)oc * CIN * KK + (size_t)ci * KK + shift] : 0.0f;
    wPT[idx] = f2bf(v);
}

__device__ __forceinline__ void fcT_body(
    const float* __restrict__ w, float* __restrict__ wT, int O, int I, int idx)
{
    if (idx >= O * I) return;
    int i = idx % I, o = idx / I;
    wT[(size_t)i * O + o] = w[idx];
}

// ---------------------------------------------------------------------------
// 1) Consolidated prep: masks + wpack x3 + ktab x3 + fcT x3 in ONE launch.
// ---------------------------------------------------------------------------
__global__ __launch_bounds__(256) void prep_k(
    const int* __restrict__ rm, unsigned long long* __restrict__ masks,
    const float* __restrict__ cw0, unsigned short* __restrict__ WP0,
    const float* __restrict__ cw1, unsigned short* __restrict__ WP1,
    const float* __restrict__ cw2, unsigned short* __restrict__ WP2,
    int* __restrict__ kt0, int* __restrict__ kt1, int* __restrict__ kt2,
    const float* __restrict__ fw0, float* __restrict__ W0T,
    const float* __restrict__ fw1, float* __restrict__ W1T,
    const float* __restrict__ fw2, float* __restrict__ W2T)
{
    const int b = blockIdx.x;
    const int t = threadIdx.x;
    if (b < 2) {
        int r = b * 256 + t;
        if (r < RR) {
            unsigned long long m = 0ull;
            #pragma unroll
            for (int k = 0; k < 64; ++k)
                if (rm[r * 64 + k]) m |= (1ull << k);
            masks[r] = m;
        }
    } else if (b < 258) {
        wpack_body(cw0, WP0, 64, 33, 25, 5, (b - 2) * 256 + t, 32 * 64 * 32);
    } else if (b < 546) {
        wpack_body(cw1, WP1, 128, 64, 9, 8, (b - 258) * 256 + t, 18 * 128 * 32);
    } else if (b < 1698) {
        wpack_body(cw2, WP2, 256, 128, 9, 16, (b - 546) * 256 + t, 36 * 256 * 32);
    } else if (b < 1699) {
        #pragma unroll
        for (int which = 0; which < 3; ++which) {
            int ngr, gpc, K, Wp, CL;
            int* dst;
            if (which == 0)      { ngr = 128; gpc = 5;  K = 5; Wp = 20; CL = 40;  dst = kt0; }
            else if (which == 1) { ngr = 72;  gpc = 8;  K = 3; Wp = 37; CL = 72;  dst = kt1; }
            else                 { ngr = 144; gpc = 16; K = 3; Wp = 19; CL = 136; dst = kt2; }
            if (t < ngr) {
                int shift = t / gpc;
                int off = 0;
                if (shift < K * K) {
                    int ky = shift / K, kx = shift % K;
                    off = (ky * Wp + kx) * CL + (t % gpc) * 8;
                }
                dst[t] = off;
            }
        }
    } else if (b < 2211) {
        fcT_body(fw0, W0T, 512, 256, (b - 1699) * 256 + t);
    } else if (b < 2723) {
        fcT_body(fw1, W1T, 256, 512, (b - 2211) * 256 + t);
    } else {
        fcT_body(fw2, W2T, 512, 256, (b - 2723) * 256 + t);
    }
}

// ---------------------------------------------------------------------------
// 2) Border zero for the two bufC padded buffers.
// ---------------------------------------------------------------------------
__device__ __forceinline__ void border_body(
    unsigned short* __restrict__ base, int Hp, int Wp, int CPG, int pad,
    int sampleStride, int nborder, int idx, int total)
{
    if (idx >= total) return;
    int c8 = idx % CPG;
    int t  = idx / CPG;
    int bi = t % nborder;
    int nl = t / nborder;

    int topN = pad * Wp;
    int y, x;
    if (bi < topN) {
        y = bi / Wp; x = bi - y * Wp;
    } else if (bi < 2 * topN) {
        int b2 = bi - topN;
        y = Hp - pad + b2 / Wp; x = b2 % Wp;
    } else {
        int mid = bi - 2 * topN;
        int rowlen = 2 * pad;
        y = pad + mid / rowlen;
        int r = mid % rowlen;
        x = r < pad ? r : Wp - pad + (r - pad);
    }
    uint4 z = make_uint4(0, 0, 0, 0);
    *reinterpret_cast<uint4*>(
        &base[((size_t)nl * sampleStride) +
              ((size_t)y * Wp + x) * (CPG * 8) + c8 * 8]) = z;
}

__global__ __launch_bounds__(256) void border2_k(
    unsigned short* __restrict__ bufC, int C_SS, int nb1, int Bc)
{
    int b = blockIdx.x;
    int t = threadIdx.x;
    if (b < nb1) {
        border_body(bufC, 37, 37, 8, 1, C_SS, 144, b * 256 + t, Bc * 144 * 8);
    } else {
        border_body(bufC + 87616, 19, 19, 16, 1, C_SS, 72,
                    (b - nb1) * 256 + t, Bc * 72 * 16);
    }
}

// ---------------------------------------------------------------------------
// 3) Encode, banded HWC. v5 + bufA halo zeroing.
// ---------------------------------------------------------------------------
__global__ __launch_bounds__(512) void encode_k(
    const int* __restrict__ X, const unsigned long long* __restrict__ masks,
    const float* __restrict__ emb, unsigned short* __restrict__ G,
    int n0, int sampleStride)
{
    __shared__ float tile[4][72][33];
    __shared__ unsigned s_pos[RR];
    __shared__ unsigned long long s_mask[RR];
    __shared__ unsigned short s_list[320];
    __shared__ float s_emb[64 * 33];
    __shared__ int s_woff[8];
    __shared__ int s_cnt;

    const int nl = blockIdx.x, band = blockIdx.y;
    const int by = band * 4;
    const int n  = n0 + nl;
    const int tid = threadIdx.x;

    float* tf = &tile[0][0][0];
    for (int i = tid; i < 4 * 72 * 33; i += 512) tf[i] = 0.0f;

    const int2* Xp = reinterpret_cast<const int2*>(X);
    bool hot = false;
    if (tid < RR) {
        int2 pos = Xp[n * RR + tid];
        s_pos[tid]  = (unsigned)pos.x | ((unsigned)pos.y << 16);
        s_mask[tid] = masks[tid];
        hot = (pos.y <= by + 3) && (pos.y + 7 >= by);
    }
    unsigned long long bal = __ballot(hot);
    if ((tid & 63) == 0) s_woff[tid >> 6] = (int)__popcll(bal);
    __syncthreads();
    if (tid == 0) {
        int acc = 0;
        #pragma unroll
        for (int w = 0; w < 8; ++w) { int c = s_woff[w]; s_woff[w] = acc; acc += c; }
        s_cnt = acc;
    }
    __syncthreads();
    if (hot) {
        int w = tid >> 6, b = tid & 63;
        unsigned long long before = (b == 0) ? 0ull : (bal & ((1ull << b) - 1ull));
        s_list[s_woff[w] + (int)__popcll(before)] = (unsigned short)tid;
    }
    __syncthreads();

    const int lane = tid & 63;
    const int wvi  = tid >> 6;
    const int dx   = lane >> 3;
    const int c0   = (lane & 7) * 5;
    const int cnt  = s_cnt;

    for (int base = 0; base < cnt; base += 64) {
        int cn = cnt - base; if (cn > 64) cn = 64;
        for (int i = tid; i < cn * 33; i += 512) {
            int hi = i / 33, cc = i - hi * 33;
            int r = s_list[base + hi];
            s_emb[i] = (cc == 0) ? 1.0f : emb[r * EMB + cc - 1];
        }
        __syncthreads();

        int j = wvi;
        for (; j + 8 < cn; j += 16) {
            int rA = s_list[base + j];
            int rB = s_list[base + j + 8];
            unsigned pA = s_pos[rA], pB = s_pos[rB];
            unsigned long long mA = s_mask[rA] >> (dx * 8);
            unsigned long long mB = s_mask[rB] >> (dx * 8);
            int xA = (pA & 0xffff) + dx, yA = pA >> 16;
            int xB = (pB & 0xffff) + dx, yB = pB >> 16;
            float eA[5], eB[5];
            #pragma unroll
            for (int q = 0; q < 5; ++q) {
                eA[q] = (c0 + q < 33) ? s_emb[j * 33 + c0 + q] : 0.0f;
                eB[q] = (c0 + q < 33) ? s_emb[(j + 8) * 33 + c0 + q] : 0.0f;
            }
            #pragma unroll
            for (int dyb = 0; dyb < 4; ++dyb) {
                int dA = by + dyb - yA;
                if ((unsigned)dA < 8u && ((mA >> dA) & 1ull)) {
                    #pragma unroll
                    for (int q = 0; q < 5; ++q)
                        if (c0 + q < 33)
                            atomicAdd(&tile[dyb][xA][c0 + q], eA[q]);
                }
                int dB = by + dyb - yB;
                if ((unsigned)dB < 8u && ((mB >> dB) & 1ull)) {
                    #pragma unroll
                    for (int q = 0; q < 5; ++q)
                        if (c0 + q < 33)
                            atomicAdd(&tile[dyb][xB][c0 + q], eB[q]);
                }
            }
        }
        for (; j < cn; j += 8) {
            int r = s_list[base + j];
            unsigned pxy = s_pos[r];
            int px = pxy & 0xffff, py = pxy >> 16;
            unsigned long long mm = s_mask[r] >> (dx * 8);
            int x = px + dx;
            float ev[5];
            #pragma unroll
            for (int q = 0; q < 5; ++q)
                ev[q] = (c0 + q < 33) ? s_emb[j * 33 + c0 + q] : 0.0f;
            #pragma unroll
            for (int dyb = 0; dyb < 4; ++dyb) {
                int dyr = by + dyb - py;
                if ((unsigned)dyr < 8u && ((mm >> dyr) & 1ull)) {
                    #pragma unroll
                    for (int q = 0; q < 5; ++q)
                        if (c0 + q < 33)
                            atomicAdd(&tile[dyb][x][c0 + q], ev[q]);
                }
            }
        }
        __syncthreads();
    }
    __syncthreads();

    unsigned short* Gn = G + (size_t)nl * sampleStride;
    for (int i = tid; i < 4 * 72 * 10; i += 512) {
        int cc = i % 10;
        int t  = i / 10;
        int x  = t % 72;
        int dyb = t / 72;
        int c0w = cc * 4;
        unsigned short r[4];
        #pragma unroll
        for (int j = 0; j < 4; ++j)
            r[j] = (c0w + j < 33) ? f2bf(tile[dyb][x][c0w + j]) : 0;
        uint2 pk;
        pk.x = (unsigned)r[0] | ((unsigned)r[1] << 16);
        pk.y = (unsigned)r[2] | ((unsigned)r[3] << 16);
        *reinterpret_cast<uint2*>(
            &Gn[((size_t)(by + dyb + 2) * 76 + (x + 2)) * 40 + c0w]) = pk;
    }

    uint2 zz; zz.x = 0; zz.y = 0;
    for (int i = tid; i < 160; i += 512) {
        int cc = i % 10;
        int t  = i / 10;
        int ci = t & 3;
        int dyb = t >> 2;
        int x = ci < 2 ? ci : 72 + ci;
        *reinterpret_cast<uint2*>(
            &Gn[((size_t)(by + dyb + 2) * 76 + x) * 40 + cc * 4]) = zz;
    }
    if (band == 0 || band == 17) {
        int rbase = band == 0 ? 0 : 74;
        for (int i = tid; i < 2 * 76 * 10; i += 512) {
            int cc = i % 10;
            int t  = i / 10;
            int x  = t % 76;
            int r  = t / 76;
            *reinterpret_cast<uint2*>(
                &Gn[((size_t)(rbase + r) * 76 + x) * 40 + cc * 4]) = zz;
        }
    }
}

// ---------------------------------------------------------------------------
// 4a) conv0: 24x16-spatial-tile implicit-GEMM, bf16 MFMA 16x16x32.
//     Round-14 body (proven fastest). No B-prefetch, (256,3), ktab in LDS.
// ---------------------------------------------------------------------------
template<int KSTEPS>
__global__ __launch_bounds__(256, 3) void conv0_tile_k(
    const unsigned short* __restrict__ inP,
    const unsigned short* __restrict__ wPT,
    const int* __restrict__ ktab,
    const float* __restrict__ bias,
    unsigned short* __restrict__ out,
    int inSS, int outSS)
{
    constexpr int CL = 40;
    constexpr int LP = 72;
    __shared__ __align__(16) unsigned short slab[28 * 20 * CL];
    __shared__ int s_kt[KSTEPS * 4];
    unsigned short* s_c = slab;

    const int tid = threadIdx.x;
    const int tl  = blockIdx.x;
    const int nl  = blockIdx.y;
    const int tyi = tl / 5, txi = tl % 5;
    const int y0 = tyi * 24;
    const int x0 = txi < 4 ? txi * 16 : 56;

    const int lane = tid & 63, wv = tid >> 6, frow = lane & 15, fq = lane >> 4;

    if (tid < KSTEPS * 4) s_kt[tid] = ktab[tid];

    const unsigned short* in_n = inP + (size_t)nl * inSS;
    {
        const uint4* src = reinterpret_cast<const uint4*>(in_n);
        uint4* dst = reinterpret_cast<uint4*>(slab);
        #pragma unroll
        for (int it = 0; it < 11; ++it) {
            int q = tid + it * 256;
            if (q < 2800) {
                int r = q / 100, c = q - r * 100;
                dst[q] = src[((y0 + r) * 76 + x0) * 5 + c];
            }
        }
    }

    int ldsb[6];
    #pragma unroll
    for (int mf = 0; mf < 6; ++mf)
        ldsb[mf] = ((mf * 4 + wv) * 20 + frow) * CL;

    const unsigned short* wbase = wPT + (size_t)frow * 32 + fq * 8;

    f32x4 acc[6][4];
    #pragma unroll
    for (int a = 0; a < 6; ++a)
        #pragma unroll
        for (int b = 0; b < 4; ++b) acc[a][b] = (f32x4){0.f, 0.f, 0.f, 0.f};

    __syncthreads();

    #pragma unroll 2
    for (int kb = 0; kb < KSTEPS; ++kb) {
        int go = s_kt[kb * 4 + fq];
        bf16x8 af[6];
        #pragma unroll
        for (int mf = 0; mf < 6; ++mf)
            af[mf] = *reinterpret_cast<const bf16x8*>(&slab[ldsb[mf] + go]);
        const unsigned short* wk = wbase + (size_t)kb * 64 * 32;
        #pragma unroll
        for (int ng = 0; ng < 4; ++ng) {
            bf16x8 bf = *reinterpret_cast<const bf16x8*>(wk + ng * 16 * 32);
            #pragma unroll
            for (int mf = 0; mf < 6; ++mf)
                acc[mf][ng] = __builtin_amdgcn_mfma_f32_16x16x32_bf16(
                    af[mf], bf, acc[mf][ng], 0, 0, 0);
        }
    }

    unsigned short* out_n = out + (size_t)nl * outSS;
    const int erow = tid >> 2, eseg = tid & 3;
    #pragma unroll
    for (int mf = 0; mf < 6; ++mf) {
        __syncthreads();
        #pragma unroll
        for (int ng = 0; ng < 4; ++ng) {
            float bv = bias[ng * 16 + frow];
            #pragma unroll
            for (int j = 0; j < 4; ++j)
                s_c[(wv * 16 + fq * 4 + j) * LP + ng * 16 + frow] =
                    f2bf(fmaxf(acc[mf][ng][j] + bv, 0.0f));
        }
        __syncthreads();
        {
            int ty = mf * 4 + (erow >> 4);
            int tx = erow & 15;
            int pos = (y0 + ty) * 72 + (x0 + tx);
            ushort8 v0 = *reinterpret_cast<const ushort8*>(
                &s_c[erow * LP + eseg * 16]);
            ushort8 v1 = *reinterpret_cast<const ushort8*>(
                &s_c[erow * LP + eseg * 16 + 8]);
            unsigned short* op = out_n + (size_t)pos * 64 + eseg * 16;
            *reinterpret_cast<ushort8*>(op) = v0;
            *reinterpret_cast<ushort8*>(op + 8) = v1;
        }
    }
}

// ---------------------------------------------------------------------------
// 4b) Generic row-slab implicit-GEMM conv (conv1/conv2), bf16 MFMA 16x16x32.
// ---------------------------------------------------------------------------
template<int MFRAG, int NG, int KH, int CPG, int CL, int SLAB, int KSTEPS>
__global__ __launch_bounds__(256, 2) void conv_mfma_k(
    const unsigned short* __restrict__ inP,
    const unsigned short* __restrict__ wPT,
    const int* __restrict__ ktab,
    const float* __restrict__ bias,
    unsigned short* __restrict__ out,
    int W, int Wp, int Mtot, int inSS, int outSS, int COUT)
{
    constexpr int Mblk = MFRAG * 64;
    constexpr int NOC  = NG * 16;
    constexpr int SEGS = NOC / 16;
    constexpr int LP   = NOC + 8;
    constexpr int CP   = CPG * 8;
    constexpr int SMEM = (SLAB * 2 > 64 * LP * 2) ? SLAB * 2 : 64 * LP * 2;
    __shared__ __align__(16) char smem[SMEM];
    __shared__ int s_kt[KSTEPS * 4];
    unsigned short* slab = reinterpret_cast<unsigned short*>(smem);
    unsigned short* s_c  = reinterpret_cast<unsigned short*>(smem);

    const int tid  = threadIdx.x;
    const int mb   = blockIdx.x;
    const int ocb  = blockIdx.y;
    const int nl   = blockIdx.z;
    const int lane = tid & 63;
    const int wv   = tid >> 6;
    const int frow = lane & 15;
    const int fq   = lane >> 4;

    if (tid < KSTEPS * 4) s_kt[tid] = ktab[tid];

    const int p0    = mb * Mblk;
    const int y0    = p0 / W;
    const int plast = (p0 + Mblk < Mtot ? p0 + Mblk : Mtot) - 1;
    const int rows  = plast / W - y0 + KH;

    const unsigned short* in_n =
        inP + (size_t)nl * inSS + (size_t)y0 * Wp * CP;
    const int nchunks = rows * Wp * CPG;
    for (int q = tid; q < nchunks; q += 256) {
        int pix = q / CPG, c8 = q - pix * CPG;
        uint4 v = reinterpret_cast<const uint4*>(in_n)[q];
        *reinterpret_cast<uint4*>(&slab[pix * CL + c8 * 8]) = v;
    }

    int ldsb[MFRAG];
    #pragma unroll
    for (int mf = 0; mf < MFRAG; ++mf) {
        int p  = p0 + mf * 64 + wv * 16 + frow;
        int pc = p < Mtot ? p : (Mtot - 1);
        int y  = pc / W;
        int x  = pc - y * W;
        ldsb[mf] = ((y - y0) * Wp + x) * CL;
    }
    const unsigned short* wbase =
        wPT + ((size_t)(ocb * NOC + frow)) * 32 + fq * 8;

    f32x4 acc[MFRAG][NG];
    #pragma unroll
    for (int mf = 0; mf < MFRAG; ++mf)
        #pragma unroll
        for (int ng = 0; ng < NG; ++ng)
            acc[mf][ng] = (f32x4){0.f, 0.f, 0.f, 0.f};

    __syncthreads();

    for (int kb = 0; kb < KSTEPS; ++kb) {
        int go = s_kt[kb * 4 + fq];
        bf16x8 af[MFRAG];
        #pragma unroll
        for (int mf = 0; mf < MFRAG; ++mf)
            af[mf] = *reinterpret_cast<const bf16x8*>(&slab[ldsb[mf] + go]);
        const unsigned short* wk = wbase + (size_t)kb * COUT * 32;
        #pragma unroll
        for (int ng = 0; ng < NG; ++ng) {
            bf16x8 bf = *reinterpret_cast<const bf16x8*>(wk + ng * 16 * 32);
            #pragma unroll
            for (int mf = 0; mf < MFRAG; ++mf)
                acc[mf][ng] = __builtin_amdgcn_mfma_f32_16x16x32_bf16(
                    af[mf], bf, acc[mf][ng], 0, 0, 0);
        }
    }

    unsigned short* out_n = out + (size_t)nl * outSS;
    #pragma unroll
    for (int mf = 0; mf < MFRAG; ++mf) {
        __syncthreads();
        #pragma unroll
        for (int ng = 0; ng < NG; ++ng) {
            float bv = bias[ocb * NOC + ng * 16 + frow];
            #pragma unroll
            for (int j = 0; j < 4; ++j)
                s_c[(wv * 16 + fq * 4 + j) * LP + ng * 16 + frow] =
                    f2bf(fmaxf(acc[mf][ng][j] + bv, 0.0f));
        }
        __syncthreads();
        for (int t = tid; t < 64 * SEGS; t += 256) {
            int row = t / SEGS, seg = t % SEGS;
            int p = p0 + mf * 64 + row;
            if (p < Mtot) {
                ushort8 v0 = *reinterpret_cast<const ushort8*>(
                    &s_c[row * LP + seg * 16]);
                ushort8 v1 = *reinterpret_cast<const ushort8*>(
                    &s_c[row * LP + seg * 16 + 8]);
                unsigned short* op =
                    out_n + (size_t)p * COUT + ocb * NOC + seg * 16;
                *reinterpret_cast<ushort8*>(op) = v0;
                *reinterpret_cast<ushort8*>(op + 8) = v1;
            }
        }
    }
}

// ---------------------------------------------------------------------------
// 5) MaxPool 3x3 s2 VALID, HWC, ushort8 (post-ReLU: u16 max).
// ---------------------------------------------------------------------------
__global__ __launch_bounds__(256) void pool_k(
    const unsigned short* __restrict__ in, unsigned short* __restrict__ out,
    int CG, int C, int W, int inSS,
    int HO, int WO, int Wpo, int outSS, int total)
{
    int idx = blockIdx.x * 256 + threadIdx.x;
    if (idx >= total) return;
    int cg = idx % CG;
    int t  = idx / CG;
    int x  = t % WO;
    t /= WO;
    int y  = t % HO;
    int nl = t / HO;

    const unsigned short* pin = in + (size_t)nl * inSS + cg * 8;
    ushort8 mx = {0,0,0,0,0,0,0,0};
    #pragma unroll
    for (int dy = 0; dy < 3; ++dy)
        #pragma unroll
        for (int dx = 0; dx < 3; ++dx) {
            ushort8 v = *reinterpret_cast<const ushort8*>(
                pin + ((size_t)(2 * y + dy) * W + (2 * x + dx)) * C);
            #pragma unroll
            for (int j = 0; j < 8; ++j) mx[j] = v[j] > mx[j] ? v[j] : mx[j];
        }
    *reinterpret_cast<ushort8*>(
        out + (size_t)nl * outSS +
        ((size_t)(y + 1) * Wpo + (x + 1)) * C + cg * 8) = mx;
}

// ---------------------------------------------------------------------------
// 6) Fused pool2 + GAP, v2: grid (Bc, 8 channel-groups) = 8x more blocks.
//    Thread = (window w, 8-ch quarter). u16 max over 3x3, then shfl_xor
//    reduce over the wave's 16 windows + LDS reduce over 4 waves.
// ---------------------------------------------------------------------------
__global__ __launch_bounds__(256) void pool2gap_k(
    const unsigned short* __restrict__ in, float* __restrict__ out,
    int inSS, int n0)
{
    __shared__ float red[4][4][8];
    const int nl = blockIdx.x;
    const int cg = blockIdx.y;          // 0..7 -> 32 channels
    const int tid = threadIdx.x;
    const int w  = tid >> 2;            // 0..63 window
    const int cq = tid & 3;             // 8-ch subgroup
    const int y = w >> 3, x = w & 7;

    const unsigned short* p = in + (size_t)nl * inSS + cg * 32 + cq * 8;
    ushort8 mx = {0,0,0,0,0,0,0,0};
    #pragma unroll
    for (int dy = 0; dy < 3; ++dy)
        #pragma unroll
        for (int dx = 0; dx < 3; ++dx) {
            ushort8 v = *reinterpret_cast<const ushort8*>(
                p + ((size_t)(2 * y + dy) * 17 + (2 * x + dx)) * 256);
            #pragma unroll
            for (int j = 0; j < 8; ++j) mx[j] = v[j] > mx[j] ? v[j] : mx[j];
        }
    float s[8];
    #pragma unroll
    for (int j = 0; j < 8; ++j) s[j] = bf2f(mx[j]);
    // reduce over the 16 windows held by this wave (lane bits 2..5)
    #pragma unroll
    for (int m = 4; m < 64; m <<= 1)
        #pragma unroll
        for (int j = 0; j < 8; ++j)
            s[j] += __shfl_xor(s[j], m);
    if ((tid & 63) < 4) {
        #pragma unroll
        for (int j = 0; j < 8; ++j) red[tid >> 6][tid & 3][j] = s[j];
    }
    __syncthreads();
    if (tid < 32) {
        int cq2 = tid >> 3, j = tid & 7;
        float t = red[0][cq2][j] + red[1][cq2][j] + red[2][cq2][j] + red[3][cq2][j];
        out[(size_t)(n0 + nl) * 256 + cg * 32 + cq2 * 8 + j] = t * (1.0f / 64.0f);
    }
}

// ---------------------------------------------------------------------------
// 7) Fused 3-layer FC head (256->512->256->512), one block per sample
// ---------------------------------------------------------------------------
__global__ __launch_bounds__(256) void fc_fused_k(
    const float* __restrict__ in,
    const float* __restrict__ w0T, const float* __restrict__ b0,
    const float* __restrict__ w1T, const float* __restrict__ b1,
    const float* __restrict__ w2T, const float* __restrict__ b2,
    float* __restrict__ out)
{
    __shared__ float s_in[256], s_h0[512], s_h1[256];
    const int n = blockIdx.x, t = threadIdx.x;
    s_in[t] = in[(size_t)n * 256 + t];
    __syncthreads();
    float a0 = 0.f, a1 = 0.f;
    for (int i = 0; i < 256; ++i) {
        float v = s_in[i];
        a0 += v * w0T[i * 512 + t];
        a1 += v * w0T[i * 512 + t + 256];
    }
    s_h0[t]       = fmaxf(a0 + b0[t], 0.0f);
    s_h0[t + 256] = fmaxf(a1 + b0[t + 256], 0.0f);
    __syncthreads();
    float h = 0.f;
    for (int i = 0; i < 512; ++i) h += s_h0[i] * w1T[i * 256 + t];
    s_h1[t] = fmaxf(h + b1[t], 0.0f);
    __syncthreads();
    a0 = 0.f; a1 = 0.f;
    for (int i = 0; i < 256; ++i) {
        float v = s_h1[i];
        a0 += v * w2T[i * 512 + t];
        a1 += v * w2T[i * 512 + t + 256];
    }
    out[(size_t)n * 512 + t]       = a0 + b2[t];
    out[(size_t)n * 512 + t + 256] = a1 + b2[t + 256];
}

// ---------------------------------------------------------------------------
// Launch. 10 kernels/call.
// ---------------------------------------------------------------------------
extern "C" void kernel_launch(void* const* d_in, const int* in_sizes, int n_in,
                              void* d_out, int out_size, void* d_ws, size_t ws_size,
                              hipStream_t stream)
{
    const int*   X   = (const int*)d_in[0];
    const int*   rm  = (const int*)d_in[1];
    const float* emb = (const float*)d_in[2];
    const float* cw0 = (const float*)d_in[3];
    const float* cb0 = (const float*)d_in[4];
    const float* cw1 = (const float*)d_in[5];
    const float* cb1 = (const float*)d_in[6];
    const float* cw2 = (const float*)d_in[7];
    const float* cb2 = (const float*)d_in[8];
    const float* fw0 = (const float*)d_in[9];
    const float* fb0 = (const float*)d_in[10];
    const float* fw1 = (const float*)d_in[11];
    const float* fb1 = (const float*)d_in[12];
    const float* fw2 = (const float*)d_in[13];
    const float* fb2 = (const float*)d_in[14];
    float* out = (float*)d_out;

    char* p = (char*)d_ws;
    auto alloc = [&](size_t bytes) -> char* {
        char* r = p; p += (bytes + 255) & ~(size_t)255; return r;
    };
    unsigned short* WP0 = (unsigned short*)alloc((size_t)32 * 64 * 32 * 2);
    unsigned short* WP1 = (unsigned short*)alloc((size_t)18 * 128 * 32 * 2);
    unsigned short* WP2 = (unsigned short*)alloc((size_t)36 * 256 * 32 * 2);
    int* KT0 = (int*)alloc(128 * 4);
    int* KT1 = (int*)alloc(72 * 4);
    int* KT2 = (int*)alloc(144 * 4);
    unsigned long long* MASKS = (unsigned long long*)alloc(RR * 8);
    float* W0T  = (float*)alloc((size_t)256 * 512 * 4);
    float* W1T  = (float*)alloc((size_t)512 * 256 * 4);
    float* W2T  = (float*)alloc((size_t)256 * 512 * 4);
    float* GAPB = (float*)alloc((size_t)NB * 256 * 4);
    size_t fixed_bytes = (size_t)(p - (char*)d_ws);

    const size_t A_FL = 231040, B_FL = 331776, C_FL = 133824;   // u16
    const size_t per_sample = (A_FL + B_FL + C_FL) * 2 + 768;
    int Bc = 128;
    while (Bc > 1 && fixed_bytes + (size_t)Bc * per_sample > ws_size) Bc >>= 1;

    unsigned short* bufA = (unsigned short*)alloc((size_t)Bc * A_FL * 2);
    unsigned short* bufC = (unsigned short*)alloc((size_t)Bc * C_FL * 2);
    unsigned short* bufB = (unsigned short*)alloc((size_t)Bc * B_FL * 2);

    // ---- consolidated prep (1 launch) ----
    prep_k<<<3235, 256, 0, stream>>>(
        rm, MASKS, cw0, WP0, cw1, WP1, cw2, WP2,
        KT0, KT1, KT2, fw0, W0T, fw1, W1T, fw2, W2T);

    // ---- chunked pipeline ----
    for (int n0 = 0; n0 < NB; n0 += Bc) {
        int nbc1 = (Bc * 144 * 8 + 255) / 256;
        int nbc2 = (Bc * 72 * 16 + 255) / 256;
        border2_k<<<nbc1 + nbc2, 256, 0, stream>>>(
            bufC, (int)C_FL, nbc1, Bc);

        // encode -> A (HWC G [76][76][40], interior +2, halo zeroed)
        encode_k<<<dim3(Bc, 18), 512, 0, stream>>>(X, MASKS, emb, bufA, n0, (int)A_FL);

        // conv0: A -> B  (15 24x16 tiles/sample, COUT=64, 32 ksteps)
        conv0_tile_k<32><<<dim3(15, Bc), 256, 0, stream>>>(
            bufA, WP0, KT0, cb0, bufB, (int)A_FL, (int)B_FL);
        // pool0: B [72][72][64] -> C P0p [37][37][64] interior +1
        pool_k<<<(Bc * 35 * 35 * 8 + 255) / 256, 256, 0, stream>>>(
            bufB, bufC, 8, 64, 72, (int)B_FL,
            35, 35, 37, (int)C_FL, Bc * 35 * 35 * 8);

        // conv1: C -> A  (M=1225, Mblk=256 -> 5 mblocks, COUT=128)
        conv_mfma_k<4, 8, 3, 8, 72, 29304, 18><<<dim3(5, 1, Bc), 256, 0, stream>>>(
            bufC, WP1, KT1, cb1, bufA, 35, 37,
            1225, (int)C_FL, (int)A_FL, 128);
        // pool1: A [35][35][128] -> C+87616 P1p [19][19][128] interior +1
        pool_k<<<(Bc * 17 * 17 * 16 + 255) / 256, 256, 0, stream>>>(
            bufA, bufC + 87616, 16, 128, 35, (int)A_FL,
            17, 17, 19, (int)C_FL, Bc * 17 * 17 * 16);

        // conv2: C+87616 -> B  (M=289, Mblk=128 -> 3 mblocks, 2 oc-blocks)
        conv_mfma_k<2, 8, 3, 16, 136, 28424, 36><<<dim3(3, 2, Bc), 256, 0, stream>>>(
            bufC + 87616, WP2, KT2, cb2, bufB, 17, 19,
            289, (int)C_FL, (int)B_FL, 256);

        // fused pool2 + GAP v2: (Bc, 8) blocks -> GAPB fp32
        pool2gap_k<<<dim3(Bc, 8), 256, 0, stream>>>(bufB, GAPB, (int)B_FL, n0);
    }

    // fused FC head
    fc_fused_k<<<NB, 256, 0, stream>>>(GAPB, W0T, fb0, W1T, fb1, W2T, fb2, out);
}

// Round 19
// 467.339 us; speedup vs baseline: 1.1108x; 1.0435x over previous
//
#include <hip/hip_runtime.h>
#include <hip/hip_bf16.h>
#include <cstdint>
#include <cstddef>

#define NB      128
#define RR      300
#define EMB     32

typedef __bf16 bf16x8 __attribute__((ext_vector_type(8)));
typedef float  f32x4  __attribute__((ext_vector_type(4)));
typedef unsigned short ushort8 __attribute__((ext_vector_type(8)));

__device__ __forceinline__ unsigned short f2bf(float f) {
    union { __hip_bfloat16 h; unsigned short u; } c;
    c.h = __float2bfloat16(f);
    return c.u;
}
__device__ __forceinline__ float bf2f(unsigned short u) {
    union { __hip_bfloat16 h; unsigned short u; } c;
    c.u = u;
    return __bfloat162float(c.h);
}

// ---------------------------------------------------------------------------
// helpers for the consolidated prep kernel
// ---------------------------------------------------------------------------
__device__ __forceinline__ void wpack_body(
    const float* __restrict__ w, unsigned short* __restrict__ wPT,
    int COUT, int CIN, int KK, int gpc, int idx, int total)
{
    if (idx >= total) return;
    int kk = idx & 31;
    int t  = idx >> 5;
    int oc = t % COUT;
    int kb = t / COUT;
    int g  = kb * 4 + (kk >> 3);
    int j  = kk & 7;
    int shift = g / gpc;
    int ci    = (g % gpc) * 8 + j;
    float v = (shift < KK && ci < CIN)
        ? w[(size_t)oc * CIN * KK + (size_t)ci * KK + shift] : 0.0f;
    wPT[idx] = f2bf(v);
}

__device__ __forceinline__ void fcT_body(
    const float* __restrict__ w, float* __restrict__ wT, int O, int I, int idx)
{
    if (idx >= O * I) return;
    int i = idx % I, o = idx / I;
    wT[(size_t)i * O + o] = w[idx];
}

// ---------------------------------------------------------------------------
// 1) Consolidated prep: masks + wpack x3 + ktab x3 + fcT x3 in ONE launch.
// ---------------------------------------------------------------------------
__global__ __launch_bounds__(256) void prep_k(
    const int* __restrict__ rm, unsigned long long* __restrict__ masks,
    const float* __restrict__ cw0, unsigned short* __restrict__ WP0,
    const float* __restrict__ cw1, unsigned short* __restrict__ WP1,
    const float* __restrict__ cw2, unsigned short* __restrict__ WP2,
    int* __restrict__ kt0, int* __restrict__ kt1, int* __restrict__ kt2,
    const float* __restrict__ fw0, float* __restrict__ W0T,
    const float* __restrict__ fw1, float* __restrict__ W1T,
    const float* __restrict__ fw2, float* __restrict__ W2T)
{
    const int b = blockIdx.x;
    const int t = threadIdx.x;
    if (b < 2) {
        int r = b * 256 + t;
        if (r < RR) {
            unsigned long long m = 0ull;
            #pragma unroll
            for (int k = 0; k < 64; ++k)
                if (rm[r * 64 + k]) m |= (1ull << k);
            masks[r] = m;
        }
    } else if (b < 258) {
        wpack_body(cw0, WP0, 64, 33, 25, 5, (b - 2) * 256 + t, 32 * 64 * 32);
    } else if (b < 546) {
        wpack_body(cw1, WP1, 128, 64, 9, 8, (b - 258) * 256 + t, 18 * 128 * 32);
    } else if (b < 1698) {
        wpack_body(cw2, WP2, 256, 128, 9, 16, (b - 546) * 256 + t, 36 * 256 * 32);
    } else if (b < 1699) {
        #pragma unroll
        for (int which = 0; which < 3; ++which) {
            int ngr, gpc, K, Wp, CL;
            int* dst;
            if (which == 0)      { ngr = 128; gpc = 5;  K = 5; Wp = 20; CL = 40;  dst = kt0; }
            else if (which == 1) { ngr = 72;  gpc = 8;  K = 3; Wp = 37; CL = 72;  dst = kt1; }
            else                 { ngr = 144; gpc = 16; K = 3; Wp = 19; CL = 136; dst = kt2; }
            if (t < ngr) {
                int shift = t / gpc;
                int off = 0;
                if (shift < K * K) {
                    int ky = shift / K, kx = shift % K;
                    off = (ky * Wp + kx) * CL + (t % gpc) * 8;
                }
                dst[t] = off;
            }
        }
    } else if (b < 2211) {
        fcT_body(fw0, W0T, 512, 256, (b - 1699) * 256 + t);
    } else if (b < 2723) {
        fcT_body(fw1, W1T, 256, 512, (b - 2211) * 256 + t);
    } else {
        fcT_body(fw2, W2T, 512, 256, (b - 2723) * 256 + t);
    }
}

// ---------------------------------------------------------------------------
// 2) border body (used as a tail inside pool launches)
// ---------------------------------------------------------------------------
__device__ __forceinline__ void border_body(
    unsigned short* __restrict__ base, int Hp, int Wp, int CPG, int pad,
    int sampleStride, int nborder, int idx, int total)
{
    if (idx >= total) return;
    int c8 = idx % CPG;
    int t  = idx / CPG;
    int bi = t % nborder;
    int nl = t / nborder;

    int topN = pad * Wp;
    int y, x;
    if (bi < topN) {
        y = bi / Wp; x = bi - y * Wp;
    } else if (bi < 2 * topN) {
        int b2 = bi - topN;
        y = Hp - pad + b2 / Wp; x = b2 % Wp;
    } else {
        int mid = bi - 2 * topN;
        int rowlen = 2 * pad;
        y = pad + mid / rowlen;
        int r = mid % rowlen;
        x = r < pad ? r : Wp - pad + (r - pad);
    }
    uint4 z = make_uint4(0, 0, 0, 0);
    *reinterpret_cast<uint4*>(
        &base[((size_t)nl * sampleStride) +
              ((size_t)y * Wp + x) * (CPG * 8) + c8 * 8]) = z;
}

// ---------------------------------------------------------------------------
// 3) Encode, banded HWC. v5 + bufA halo zeroing.
// ---------------------------------------------------------------------------
__global__ __launch_bounds__(512) void encode_k(
    const int* __restrict__ X, const unsigned long long* __restrict__ masks,
    const float* __restrict__ emb, unsigned short* __restrict__ G,
    int n0, int sampleStride)
{
    __shared__ float tile[4][72][33];
    __shared__ unsigned s_pos[RR];
    __shared__ unsigned long long s_mask[RR];
    __shared__ unsigned short s_list[320];
    __shared__ float s_emb[64 * 33];
    __shared__ int s_woff[8];
    __shared__ int s_cnt;

    const int nl = blockIdx.x, band = blockIdx.y;
    const int by = band * 4;
    const int n  = n0 + nl;
    const int tid = threadIdx.x;

    float* tf = &tile[0][0][0];
    for (int i = tid; i < 4 * 72 * 33; i += 512) tf[i] = 0.0f;

    const int2* Xp = reinterpret_cast<const int2*>(X);
    bool hot = false;
    if (tid < RR) {
        int2 pos = Xp[n * RR + tid];
        s_pos[tid]  = (unsigned)pos.x | ((unsigned)pos.y << 16);
        s_mask[tid] = masks[tid];
        hot = (pos.y <= by + 3) && (pos.y + 7 >= by);
    }
    unsigned long long bal = __ballot(hot);
    if ((tid & 63) == 0) s_woff[tid >> 6] = (int)__popcll(bal);
    __syncthreads();
    if (tid == 0) {
        int acc = 0;
        #pragma unroll
        for (int w = 0; w < 8; ++w) { int c = s_woff[w]; s_woff[w] = acc; acc += c; }
        s_cnt = acc;
    }
    __syncthreads();
    if (hot) {
        int w = tid >> 6, b = tid & 63;
        unsigned long long before = (b == 0) ? 0ull : (bal & ((1ull << b) - 1ull));
        s_list[s_woff[w] + (int)__popcll(before)] = (unsigned short)tid;
    }
    __syncthreads();

    const int lane = tid & 63;
    const int wvi  = tid >> 6;
    const int dx   = lane >> 3;
    const int c0   = (lane & 7) * 5;
    const int cnt  = s_cnt;

    for (int base = 0; base < cnt; base += 64) {
        int cn = cnt - base; if (cn > 64) cn = 64;
        for (int i = tid; i < cn * 33; i += 512) {
            int hi = i / 33, cc = i - hi * 33;
            int r = s_list[base + hi];
            s_emb[i] = (cc == 0) ? 1.0f : emb[r * EMB + cc - 1];
        }
        __syncthreads();

        int j = wvi;
        for (; j + 8 < cn; j += 16) {
            int rA = s_list[base + j];
            int rB = s_list[base + j + 8];
            unsigned pA = s_pos[rA], pB = s_pos[rB];
            unsigned long long mA = s_mask[rA] >> (dx * 8);
            unsigned long long mB = s_mask[rB] >> (dx * 8);
            int xA = (pA & 0xffff) + dx, yA = pA >> 16;
            int xB = (pB & 0xffff) + dx, yB = pB >> 16;
            float eA[5], eB[5];
            #pragma unroll
            for (int q = 0; q < 5; ++q) {
                eA[q] = (c0 + q < 33) ? s_emb[j * 33 + c0 + q] : 0.0f;
                eB[q] = (c0 + q < 33) ? s_emb[(j + 8) * 33 + c0 + q] : 0.0f;
            }
            #pragma unroll
            for (int dyb = 0; dyb < 4; ++dyb) {
                int dA = by + dyb - yA;
                if ((unsigned)dA < 8u && ((mA >> dA) & 1ull)) {
                    #pragma unroll
                    for (int q = 0; q < 5; ++q)
                        if (c0 + q < 33)
                            atomicAdd(&tile[dyb][xA][c0 + q], eA[q]);
                }
                int dB = by + dyb - yB;
                if ((unsigned)dB < 8u && ((mB >> dB) & 1ull)) {
                    #pragma unroll
                    for (int q = 0; q < 5; ++q)
                        if (c0 + q < 33)
                            atomicAdd(&tile[dyb][xB][c0 + q], eB[q]);
                }
            }
        }
        for (; j < cn; j += 8) {
            int r = s_list[base + j];
            unsigned pxy = s_pos[r];
            int px = pxy & 0xffff, py = pxy >> 16;
            unsigned long long mm = s_mask[r] >> (dx * 8);
            int x = px + dx;
            float ev[5];
            #pragma unroll
            for (int q = 0; q < 5; ++q)
                ev[q] = (c0 + q < 33) ? s_emb[j * 33 + c0 + q] : 0.0f;
            #pragma unroll
            for (int dyb = 0; dyb < 4; ++dyb) {
                int dyr = by + dyb - py;
                if ((unsigned)dyr < 8u && ((mm >> dyr) & 1ull)) {
                    #pragma unroll
                    for (int q = 0; q < 5; ++q)
                        if (c0 + q < 33)
                            atomicAdd(&tile[dyb][x][c0 + q], ev[q]);
                }
            }
        }
        __syncthreads();
    }
    __syncthreads();

    unsigned short* Gn = G + (size_t)nl * sampleStride;
    for (int i = tid; i < 4 * 72 * 10; i += 512) {
        int cc = i % 10;
        int t  = i / 10;
        int x  = t % 72;
        int dyb = t / 72;
        int c0w = cc * 4;
        unsigned short r[4];
        #pragma unroll
        for (int j = 0; j < 4; ++j)
            r[j] = (c0w + j < 33) ? f2bf(tile[dyb][x][c0w + j]) : 0;
        uint2 pk;
        pk.x = (unsigned)r[0] | ((unsigned)r[1] << 16);
        pk.y = (unsigned)r[2] | ((unsigned)r[3] << 16);
        *reinterpret_cast<uint2*>(
            &Gn[((size_t)(by + dyb + 2) * 76 + (x + 2)) * 40 + c0w]) = pk;
    }

    uint2 zz; zz.x = 0; zz.y = 0;
    for (int i = tid; i < 160; i += 512) {
        int cc = i % 10;
        int t  = i / 10;
        int ci = t & 3;
        int dyb = t >> 2;
        int x = ci < 2 ? ci : 72 + ci;
        *reinterpret_cast<uint2*>(
            &Gn[((size_t)(by + dyb + 2) * 76 + x) * 40 + cc * 4]) = zz;
    }
    if (band == 0 || band == 17) {
        int rbase = band == 0 ? 0 : 74;
        for (int i = tid; i < 2 * 76 * 10; i += 512) {
            int cc = i % 10;
            int t  = i / 10;
            int x  = t % 76;
            int r  = t / 76;
            *reinterpret_cast<uint2*>(
                &Gn[((size_t)(rbase + r) * 76 + x) * 40 + cc * 4]) = zz;
        }
    }
}

// ---------------------------------------------------------------------------
// 4a) conv0: 24x16-spatial-tile implicit-GEMM, bf16 MFMA 16x16x32.
//     Round-14 body (proven fastest). No B-prefetch, (256,3), ktab in LDS.
// ---------------------------------------------------------------------------
template<int KSTEPS>
__global__ __launch_bounds__(256, 3) void conv0_tile_k(
    const unsigned short* __restrict__ inP,
    const unsigned short* __restrict__ wPT,
    const int* __restrict__ ktab,
    const float* __restrict__ bias,
    unsigned short* __restrict__ out,
    int inSS, int outSS)
{
    constexpr int CL = 40;
    constexpr int LP = 72;
    __shared__ __align__(16) unsigned short slab[28 * 20 * CL];
    __shared__ int s_kt[KSTEPS * 4];
    unsigned short* s_c = slab;

    const int tid = threadIdx.x;
    const int tl  = blockIdx.x;
    const int nl  = blockIdx.y;
    const int tyi = tl / 5, txi = tl % 5;
    const int y0 = tyi * 24;
    const int x0 = txi < 4 ? txi * 16 : 56;

    const int lane = tid & 63, wv = tid >> 6, frow = lane & 15, fq = lane >> 4;

    if (tid < KSTEPS * 4) s_kt[tid] = ktab[tid];

    const unsigned short* in_n = inP + (size_t)nl * inSS;
    {
        const uint4* src = reinterpret_cast<const uint4*>(in_n);
        uint4* dst = reinterpret_cast<uint4*>(slab);
        #pragma unroll
        for (int it = 0; it < 11; ++it) {
            int q = tid + it * 256;
            if (q < 2800) {
                int r = q / 100, c = q - r * 100;
                dst[q] = src[((y0 + r) * 76 + x0) * 5 + c];
            }
        }
    }

    int ldsb[6];
    #pragma unroll
    for (int mf = 0; mf < 6; ++mf)
        ldsb[mf] = ((mf * 4 + wv) * 20 + frow) * CL;

    const unsigned short* wbase = wPT + (size_t)frow * 32 + fq * 8;

    f32x4 acc[6][4];
    #pragma unroll
    for (int a = 0; a < 6; ++a)
        #pragma unroll
        for (int b = 0; b < 4; ++b) acc[a][b] = (f32x4){0.f, 0.f, 0.f, 0.f};

    __syncthreads();

    #pragma unroll 2
    for (int kb = 0; kb < KSTEPS; ++kb) {
        int go = s_kt[kb * 4 + fq];
        bf16x8 af[6];
        #pragma unroll
        for (int mf = 0; mf < 6; ++mf)
            af[mf] = *reinterpret_cast<const bf16x8*>(&slab[ldsb[mf] + go]);
        const unsigned short* wk = wbase + (size_t)kb * 64 * 32;
        #pragma unroll
        for (int ng = 0; ng < 4; ++ng) {
            bf16x8 bf = *reinterpret_cast<const bf16x8*>(wk + ng * 16 * 32);
            #pragma unroll
            for (int mf = 0; mf < 6; ++mf)
                acc[mf][ng] = __builtin_amdgcn_mfma_f32_16x16x32_bf16(
                    af[mf], bf, acc[mf][ng], 0, 0, 0);
        }
    }

    unsigned short* out_n = out + (size_t)nl * outSS;
    const int erow = tid >> 2, eseg = tid & 3;
    #pragma unroll
    for (int mf = 0; mf < 6; ++mf) {
        __syncthreads();
        #pragma unroll
        for (int ng = 0; ng < 4; ++ng) {
            float bv = bias[ng * 16 + frow];
            #pragma unroll
            for (int j = 0; j < 4; ++j)
                s_c[(wv * 16 + fq * 4 + j) * LP + ng * 16 + frow] =
                    f2bf(fmaxf(acc[mf][ng][j] + bv, 0.0f));
        }
        __syncthreads();
        {
            int ty = mf * 4 + (erow >> 4);
            int tx = erow & 15;
            int pos = (y0 + ty) * 72 + (x0 + tx);
            ushort8 v0 = *reinterpret_cast<const ushort8*>(
                &s_c[erow * LP + eseg * 16]);
            ushort8 v1 = *reinterpret_cast<const ushort8*>(
                &s_c[erow * LP + eseg * 16 + 8]);
            unsigned short* op = out_n + (size_t)pos * 64 + eseg * 16;
            *reinterpret_cast<ushort8*>(op) = v0;
            *reinterpret_cast<ushort8*>(op + 8) = v1;
        }
    }
}

// ---------------------------------------------------------------------------
// 4b) Generic row-slab implicit-GEMM conv (conv1/conv2), bf16 MFMA 16x16x32.
// ---------------------------------------------------------------------------
template<int MFRAG, int NG, int KH, int CPG, int CL, int SLAB, int KSTEPS>
__global__ __launch_bounds__(256, 2) void conv_mfma_k(
    const unsigned short* __restrict__ inP,
    const unsigned short* __restrict__ wPT,
    const int* __restrict__ ktab,
    const float* __restrict__ bias,
    unsigned short* __restrict__ out,
    int W, int Wp, int Mtot, int inSS, int outSS, int COUT)
{
    constexpr int Mblk = MFRAG * 64;
    constexpr int NOC  = NG * 16;
    constexpr int SEGS = NOC / 16;
    constexpr int LP   = NOC + 8;
    constexpr int CP   = CPG * 8;
    constexpr int SMEM = (SLAB * 2 > 64 * LP * 2) ? SLAB * 2 : 64 * LP * 2;
    __shared__ __align__(16) char smem[SMEM];
    __shared__ int s_kt[KSTEPS * 4];
    unsigned short* slab = reinterpret_cast<unsigned short*>(smem);
    unsigned short* s_c  = reinterpret_cast<unsigned short*>(smem);

    const int tid  = threadIdx.x;
    const int mb   = blockIdx.x;
    const int ocb  = blockIdx.y;
    const int nl   = blockIdx.z;
    const int lane = tid & 63;
    const int wv   = tid >> 6;
    const int frow = lane & 15;
    const int fq   = lane >> 4;

    if (tid < KSTEPS * 4) s_kt[tid] = ktab[tid];

    const int p0    = mb * Mblk;
    const int y0    = p0 / W;
    const int plast = (p0 + Mblk < Mtot ? p0 + Mblk : Mtot) - 1;
    const int rows  = plast / W - y0 + KH;

    const unsigned short* in_n =
        inP + (size_t)nl * inSS + (size_t)y0 * Wp * CP;
    const int nchunks = rows * Wp * CPG;
    for (int q = tid; q < nchunks; q += 256) {
        int pix = q / CPG, c8 = q - pix * CPG;
        uint4 v = reinterpret_cast<const uint4*>(in_n)[q];
        *reinterpret_cast<uint4*>(&slab[pix * CL + c8 * 8]) = v;
    }

    int ldsb[MFRAG];
    #pragma unroll
    for (int mf = 0; mf < MFRAG; ++mf) {
        int p  = p0 + mf * 64 + wv * 16 + frow;
        int pc = p < Mtot ? p : (Mtot - 1);
        int y  = pc / W;
        int x  = pc - y * W;
        ldsb[mf] = ((y - y0) * Wp + x) * CL;
    }
    const unsigned short* wbase =
        wPT + ((size_t)(ocb * NOC + frow)) * 32 + fq * 8;

    f32x4 acc[MFRAG][NG];
    #pragma unroll
    for (int mf = 0; mf < MFRAG; ++mf)
        #pragma unroll
        for (int ng = 0; ng < NG; ++ng)
            acc[mf][ng] = (f32x4){0.f, 0.f, 0.f, 0.f};

    __syncthreads();

    for (int kb = 0; kb < KSTEPS; ++kb) {
        int go = s_kt[kb * 4 + fq];
        bf16x8 af[MFRAG];
        #pragma unroll
        for (int mf = 0; mf < MFRAG; ++mf)
            af[mf] = *reinterpret_cast<const bf16x8*>(&slab[ldsb[mf] + go]);
        const unsigned short* wk = wbase + (size_t)kb * COUT * 32;
        #pragma unroll
        for (int ng = 0; ng < NG; ++ng) {
            bf16x8 bf = *reinterpret_cast<const bf16x8*>(wk + ng * 16 * 32);
            #pragma unroll
            for (int mf = 0; mf < MFRAG; ++mf)
                acc[mf][ng] = __builtin_amdgcn_mfma_f32_16x16x32_bf16(
                    af[mf], bf, acc[mf][ng], 0, 0, 0);
        }
    }

    unsigned short* out_n = out + (size_t)nl * outSS;
    #pragma unroll
    for (int mf = 0; mf < MFRAG; ++mf) {
        __syncthreads();
        #pragma unroll
        for (int ng = 0; ng < NG; ++ng) {
            float bv = bias[ocb * NOC + ng * 16 + frow];
            #pragma unroll
            for (int j = 0; j < 4; ++j)
                s_c[(wv * 16 + fq * 4 + j) * LP + ng * 16 + frow] =
                    f2bf(fmaxf(acc[mf][ng][j] + bv, 0.0f));
        }
        __syncthreads();
        for (int t = tid; t < 64 * SEGS; t += 256) {
            int row = t / SEGS, seg = t % SEGS;
            int p = p0 + mf * 64 + row;
            if (p < Mtot) {
                ushort8 v0 = *reinterpret_cast<const ushort8*>(
                    &s_c[row * LP + seg * 16]);
                ushort8 v1 = *reinterpret_cast<const ushort8*>(
                    &s_c[row * LP + seg * 16 + 8]);
                unsigned short* op =
                    out_n + (size_t)p * COUT + ocb * NOC + seg * 16;
                *reinterpret_cast<ushort8*>(op) = v0;
                *reinterpret_cast<ushort8*>(op + 8) = v1;
            }
        }
    }
}

// ---------------------------------------------------------------------------
// 5) MaxPool 3x3 s2 VALID, HWC, ushort8 + fused halo-zero tail for the
//    output buffer (blocks >= npool do border zeroing; disjoint addresses).
// ---------------------------------------------------------------------------
__global__ __launch_bounds__(256) void pool_border_k(
    const unsigned short* __restrict__ in, unsigned short* __restrict__ out,
    int CG, int C, int W, int inSS,
    int HO, int WO, int Wpo, int outSS, int total,
    int npool, int bHp, int bWp, int bCPG, int bpad, int bnborder, int btotal)
{
    const int b = blockIdx.x;
    const int tidx = threadIdx.x;
    if (b >= npool) {
        border_body(out, bHp, bWp, bCPG, bpad, outSS, bnborder,
                    (b - npool) * 256 + tidx, btotal);
        return;
    }
    int idx = b * 256 + tidx;
    if (idx >= total) return;
    int cg = idx % CG;
    int t  = idx / CG;
    int x  = t % WO;
    t /= WO;
    int y  = t % HO;
    int nl = t / HO;

    const unsigned short* pin = in + (size_t)nl * inSS + cg * 8;
    ushort8 mx = {0,0,0,0,0,0,0,0};
    #pragma unroll
    for (int dy = 0; dy < 3; ++dy)
        #pragma unroll
        for (int dx = 0; dx < 3; ++dx) {
            ushort8 v = *reinterpret_cast<const ushort8*>(
                pin + ((size_t)(2 * y + dy) * W + (2 * x + dx)) * C);
            #pragma unroll
            for (int j = 0; j < 8; ++j) mx[j] = v[j] > mx[j] ? v[j] : mx[j];
        }
    *reinterpret_cast<ushort8*>(
        out + (size_t)nl * outSS +
        ((size_t)(y + 1) * Wpo + (x + 1)) * C + cg * 8) = mx;
}

// ---------------------------------------------------------------------------
// 6) Fused pool2 + GAP, v2 (grid (Bc,8), shfl reduce).
// ---------------------------------------------------------------------------
__global__ __launch_bounds__(256) void pool2gap_k(
    const unsigned short* __restrict__ in, float* __restrict__ out,
    int inSS, int n0)
{
    __shared__ float red[4][4][8];
    const int nl = blockIdx.x;
    const int cg = blockIdx.y;
    const int tid = threadIdx.x;
    const int w  = tid >> 2;
    const int cq = tid & 3;
    const int y = w >> 3, x = w & 7;

    const unsigned short* p = in + (size_t)nl * inSS + cg * 32 + cq * 8;
    ushort8 mx = {0,0,0,0,0,0,0,0};
    #pragma unroll
    for (int dy = 0; dy < 3; ++dy)
        #pragma unroll
        for (int dx = 0; dx < 3; ++dx) {
            ushort8 v = *reinterpret_cast<const ushort8*>(
                p + ((size_t)(2 * y + dy) * 17 + (2 * x + dx)) * 256);
            #pragma unroll
            for (int j = 0; j < 8; ++j) mx[j] = v[j] > mx[j] ? v[j] : mx[j];
        }
    float s[8];
    #pragma unroll
    for (int j = 0; j < 8; ++j) s[j] = bf2f(mx[j]);
    #pragma unroll
    for (int m = 4; m < 64; m <<= 1)
        #pragma unroll
        for (int j = 0; j < 8; ++j)
            s[j] += __shfl_xor(s[j], m);
    if ((tid & 63) < 4) {
        #pragma unroll
        for (int j = 0; j < 8; ++j) red[tid >> 6][tid & 3][j] = s[j];
    }
    __syncthreads();
    if (tid < 32) {
        int cq2 = tid >> 3, j = tid & 7;
        float t = red[0][cq2][j] + red[1][cq2][j] + red[2][cq2][j] + red[3][cq2][j];
        out[(size_t)(n0 + nl) * 256 + cg * 32 + cq2 * 8 + j] = t * (1.0f / 64.0f);
    }
}

// ---------------------------------------------------------------------------
// 7) Fused 3-layer FC head (256->512->256->512), one block per sample
// ---------------------------------------------------------------------------
__global__ __launch_bounds__(256) void fc_fused_k(
    const float* __restrict__ in,
    const float* __restrict__ w0T, const float* __restrict__ b0,
    const float* __restrict__ w1T, const float* __restrict__ b1,
    const float* __restrict__ w2T, const float* __restrict__ b2,
    float* __restrict__ out)
{
    __shared__ float s_in[256], s_h0[512], s_h1[256];
    const int n = blockIdx.x, t = threadIdx.x;
    s_in[t] = in[(size_t)n * 256 + t];
    __syncthreads();
    float a0 = 0.f, a1 = 0.f;
    for (int i = 0; i < 256; ++i) {
        float v = s_in[i];
        a0 += v * w0T[i * 512 + t];
        a1 += v * w0T[i * 512 + t + 256];
    }
    s_h0[t]       = fmaxf(a0 + b0[t], 0.0f);
    s_h0[t + 256] = fmaxf(a1 + b0[t + 256], 0.0f);
    __syncthreads();
    float h = 0.f;
    for (int i = 0; i < 512; ++i) h += s_h0[i] * w1T[i * 256 + t];
    s_h1[t] = fmaxf(h + b1[t], 0.0f);
    __syncthreads();
    a0 = 0.f; a1 = 0.f;
    for (int i = 0; i < 256; ++i) {
        float v = s_h1[i];
        a0 += v * w2T[i * 512 + t];
        a1 += v * w2T[i * 512 + t + 256];
    }
    out[(size_t)n * 512 + t]       = a0 + b2[t];
    out[(size_t)n * 512 + t + 256] = a1 + b2[t + 256];
}

// ---------------------------------------------------------------------------
// Launch. 9 kernels/call.
// ---------------------------------------------------------------------------
extern "C" void kernel_launch(void* const* d_in, const int* in_sizes, int n_in,
                              void* d_out, int out_size, void* d_ws, size_t ws_size,
                              hipStream_t stream)
{
    const int*   X   = (const int*)d_in[0];
    const int*   rm  = (const int*)d_in[1];
    const float* emb = (const float*)d_in[2];
    const float* cw0 = (const float*)d_in[3];
    const float* cb0 = (const float*)d_in[4];
    const float* cw1 = (const float*)d_in[5];
    const float* cb1 = (const float*)d_in[6];
    const float* cw2 = (const float*)d_in[7];
    const float* cb2 = (const float*)d_in[8];
    const float* fw0 = (const float*)d_in[9];
    const float* fb0 = (const float*)d_in[10];
    const float* fw1 = (const float*)d_in[11];
    const float* fb1 = (const float*)d_in[12];
    const float* fw2 = (const float*)d_in[13];
    const float* fb2 = (const float*)d_in[14];
    float* out = (float*)d_out;

    char* p = (char*)d_ws;
    auto alloc = [&](size_t bytes) -> char* {
        char* r = p; p += (bytes + 255) & ~(size_t)255; return r;
    };
    unsigned short* WP0 = (unsigned short*)alloc((size_t)32 * 64 * 32 * 2);
    unsigned short* WP1 = (unsigned short*)alloc((size_t)18 * 128 * 32 * 2);
    unsigned short* WP2 = (unsigned short*)alloc((size_t)36 * 256 * 32 * 2);
    int* KT0 = (int*)alloc(128 * 4);
    int* KT1 = (int*)alloc(72 * 4);
    int* KT2 = (int*)alloc(144 * 4);
    unsigned long long* MASKS = (unsigned long long*)alloc(RR * 8);
    float* W0T  = (float*)alloc((size_t)256 * 512 * 4);
    float* W1T  = (float*)alloc((size_t)512 * 256 * 4);
    float* W2T  = (float*)alloc((size_t)256 * 512 * 4);
    float* GAPB = (float*)alloc((size_t)NB * 256 * 4);
    size_t fixed_bytes = (size_t)(p - (char*)d_ws);

    const size_t A_FL = 231040, B_FL = 331776, C_FL = 133824;   // u16
    const size_t per_sample = (A_FL + B_FL + C_FL) * 2 + 768;
    int Bc = 128;
    while (Bc > 1 && fixed_bytes + (size_t)Bc * per_sample > ws_size) Bc >>= 1;

    unsigned short* bufA = (unsigned short*)alloc((size_t)Bc * A_FL * 2);
    unsigned short* bufC = (unsigned short*)alloc((size_t)Bc * C_FL * 2);
    unsigned short* bufB = (unsigned short*)alloc((size_t)Bc * B_FL * 2);

    // ---- consolidated prep (1 launch) ----
    prep_k<<<3235, 256, 0, stream>>>(
        rm, MASKS, cw0, WP0, cw1, WP1, cw2, WP2,
        KT0, KT1, KT2, fw0, W0T, fw1, W1T, fw2, W2T);

    // ---- chunked pipeline ----
    for (int n0 = 0; n0 < NB; n0 += Bc) {
        // encode -> A (HWC G [76][76][40], interior +2, halo zeroed)
        encode_k<<<dim3(Bc, 18), 512, 0, stream>>>(X, MASKS, emb, bufA, n0, (int)A_FL);

        // conv0: A -> B  (15 24x16 tiles/sample, COUT=64, 32 ksteps)
        conv0_tile_k<32><<<dim3(15, Bc), 256, 0, stream>>>(
            bufA, WP0, KT0, cb0, bufB, (int)A_FL, (int)B_FL);

        // pool0 + P0p-halo zero: B [72][72][64] -> C P0p [37][37][64]
        {
            int total = Bc * 35 * 35 * 8;
            int npool = (total + 255) / 256;
            int btotal = Bc * 144 * 8;
            int nbord = (btotal + 255) / 256;
            pool_border_k<<<npool + nbord, 256, 0, stream>>>(
                bufB, bufC, 8, 64, 72, (int)B_FL,
                35, 35, 37, (int)C_FL, total,
                npool, 37, 37, 8, 1, 144, btotal);
        }

        // conv1: C -> A  (M=1225, Mblk=256 -> 5 mblocks, COUT=128)
        conv_mfma_k<4, 8, 3, 8, 72, 29304, 18><<<dim3(5, 1, Bc), 256, 0, stream>>>(
            bufC, WP1, KT1, cb1, bufA, 35, 37,
            1225, (int)C_FL, (int)A_FL, 128);

        // pool1 + P1p-halo zero: A [35][35][128] -> C+87616 P1p [19][19][128]
        {
            int total = Bc * 17 * 17 * 16;
            int npool = (total + 255) / 256;
            int btotal = Bc * 72 * 16;
            int nbord = (btotal + 255) / 256;
            pool_border_k<<<npool + nbord, 256, 0, stream>>>(
                bufA, bufC + 87616, 16, 128, 35, (int)A_FL,
                17, 17, 19, (int)C_FL, total,
                npool, 19, 19, 16, 1, 72, btotal);
        }

        // conv2: C+87616 -> B  (M=289, single Mblk=320, 2 oc-blocks,
        //        slab = whole sample input 19x19x136 = 98KB, 256 blocks)
        conv_mfma_k<5, 8, 3, 16, 136, 49096, 36><<<dim3(1, 2, Bc), 256, 0, stream>>>(
            bufC + 87616, WP2, KT2, cb2, bufB, 17, 19,
            289, (int)C_FL, (int)B_FL, 256);

        // fused pool2 + GAP v2: (Bc, 8) blocks -> GAPB fp32
        pool2gap_k<<<dim3(Bc, 8), 256, 0, stream>>>(bufB, GAPB, (int)B_FL, n0);
    }

    // fused FC head
    fc_fused_k<<<NB, 256, 0, stream>>>(GAPB, W0T, fb0, W1T, fb1, W2T, fb2, out);
}